// Round 15
// baseline (450.572 us; speedup 1.0000x reference)
//
#include <hip/hip_runtime.h>

#define T_TOK 4096
#define HDIM  1024
#define NEXP  8
#define FFDIM 4096
#define NPAIR 8192   // T_TOK * topk
#define MAXMT 40     // max total 256-row M-tiles across experts: 8192/256 + 8

typedef __attribute__((ext_vector_type(8))) short short8;
typedef __attribute__((ext_vector_type(8))) unsigned short ushort8;
typedef __attribute__((ext_vector_type(4))) float f32x4;

__device__ __forceinline__ unsigned short f2bf(float f) {
  unsigned int u = __float_as_uint(f);
  u += 0x7fffu + ((u >> 16) & 1u);   // RNE
  return (unsigned short)(u >> 16);
}

// global -> LDS direct copy, 16B per lane. LDS dest is wave-uniform base;
// HW writes lane l at base + l*16. Global source address is per-lane.
__device__ __forceinline__ void gload16(const void* g, const void* l) {
  __builtin_amdgcn_global_load_lds(
      (const __attribute__((address_space(1))) unsigned int*)(unsigned long long)g,
      (__attribute__((address_space(3))) unsigned int*)(unsigned int)(unsigned long long)l,
      16, 0, 0);
}

// ---------------- transpose v2 (r14, kept) ----------------
__global__ __launch_bounds__(256) void transpose_bf16_kernel(
    const float* __restrict__ in, unsigned short* __restrict__ out, int M, int N) {
  in  += (size_t)blockIdx.z * M * N;
  out += (size_t)blockIdx.z * M * N;
  __shared__ unsigned short t[64][264];
  int tid = threadIdx.x;
  int r0 = blockIdx.y * 256, c0 = blockIdx.x * 64;
  int colb = (tid & 15) * 4;
  int rowi = tid >> 4;
  int sw = (tid & 7) << 3;
#pragma unroll
  for (int i = 0; i < 16; i++) {
    int row = i * 16 + rowi;
    float4 v = *(const float4*)(in + (size_t)(r0 + row) * N + c0 + colb);
    int rs = row ^ sw;
    t[colb + 0][rs] = f2bf(v.x);
    t[colb + 1][rs] = f2bf(v.y);
    t[colb + 2][rs] = f2bf(v.z);
    t[colb + 3][rs] = f2bf(v.w);
  }
  __syncthreads();
  int m0 = (tid & 31) * 8;
  int nsub = tid >> 5;
#pragma unroll
  for (int i = 0; i < 8; i++) {
    int n = i * 8 + nsub;
    int sn = ((n >> 2) & 7) << 3;
    ushort8 v = *(const ushort8*)&t[n][m0 ^ sn];
    *(ushort8*)(out + (size_t)(c0 + n) * M + r0 + m0) = v;
  }
}

// ---------------- router (fused: also emits bf16 x) ----------------

__global__ __launch_bounds__(256) void router_kernel(
    const float* __restrict__ x, const float* __restrict__ wg,
    unsigned short* __restrict__ xb,
    int* __restrict__ sel_e, float* __restrict__ sel_w, int* __restrict__ counts) {
  int lane = threadIdx.x & 63;
  int t = blockIdx.x * 4 + (threadIdx.x >> 6);
  const float* xr = x + (size_t)t * HDIM;
  unsigned short* xo = xb + (size_t)t * HDIM;
  float acc[8] = {0, 0, 0, 0, 0, 0, 0, 0};
  for (int i = 0; i < HDIM / 64; i++) {
    int h = i * 64 + lane;
    float xv = xr[h];
    xo[h] = f2bf(xv);                        // fused convert_x
    float4 w0 = *(const float4*)(wg + h * 8);
    float4 w1 = *(const float4*)(wg + h * 8 + 4);
    acc[0] += xv * w0.x; acc[1] += xv * w0.y; acc[2] += xv * w0.z; acc[3] += xv * w0.w;
    acc[4] += xv * w1.x; acc[5] += xv * w1.y; acc[6] += xv * w1.z; acc[7] += xv * w1.w;
  }
#pragma unroll
  for (int off = 32; off > 0; off >>= 1) {
#pragma unroll
    for (int e = 0; e < 8; e++) acc[e] += __shfl_xor(acc[e], off, 64);
  }
  if (lane == 0) {
    int e0 = 0; float b0 = acc[0];
#pragma unroll
    for (int e = 1; e < 8; e++) if (acc[e] > b0) { b0 = acc[e]; e0 = e; }
    int e1 = -1; float b1 = -3.4e38f;
#pragma unroll
    for (int e = 0; e < 8; e++) if (e != e0 && acc[e] > b1) { b1 = acc[e]; e1 = e; }
    float q = expf(b1 - b0);                 // softmax denominator cancels in renorm
    float w0 = 1.0f / (1.0f + q);
    float w1 = q / (1.0f + q);
    sel_e[t * 2] = e0; sel_e[t * 2 + 1] = e1;
    sel_w[t * 2] = w0; sel_w[t * 2 + 1] = w1;
    atomicAdd(&counts[e0], 1);
    atomicAdd(&counts[e1], 1);
  }
}

__global__ void offsets_kernel(const int* __restrict__ counts,
                               int* __restrict__ offsets, int* __restrict__ cursor) {
  if (threadIdx.x == 0 && blockIdx.x == 0) {
    int s = 0;
    for (int e = 0; e < NEXP; e++) { offsets[e] = s; cursor[e] = s; s += counts[e]; }
  }
}

__global__ __launch_bounds__(256) void scatter_kernel(
    const int* __restrict__ sel_e, const float* __restrict__ sel_w,
    int* __restrict__ cursor, int* __restrict__ pair_token, float* __restrict__ pair_w) {
  int t = blockIdx.x * 256 + threadIdx.x;
#pragma unroll
  for (int j = 0; j < 2; j++) {
    int e = sel_e[t * 2 + j];
    int pos = atomicAdd(&cursor[e], 1);
    pair_token[pos] = t;
    pair_w[pos] = sel_w[t * 2 + j];
  }
}

// --- expert GEMMs: r13 schedule, 128x64 WAVE tiles (LDS-burst fix) ---
// Cycle accounting on r13 (129us): interval ~2150cyc, of which ~1540 = the
// post-barrier ds_read burst (16 waves/CU x 8 b128 @ ~12cyc, LDS pipe ~85B/cyc
// per CU). Lever = LDS bytes/FLOP = (m+n)/(m*n): 64x64 -> 0.031, 128x64 ->
// 0.023 (-25%). r10/r12's 128x64 failed from 1-block/CU convoys, not the tile.
// Config: block 256M x 128N, 4 waves (2M x 2N), wave tile 128x64, acc[8][4]
// (128 AGPR + ~85 VGPR ~ 215 regs -> 2 waves/SIMD), BK=32, 3-slot ring 24KB
// -> 72KB LDS -> 2 blocks/CU (8 waves/CU). Per K-tile (r13 skeleton):
//   vmcnt(6) [own newest 6 = t+1's, tile t proven] -> s_barrier -> 12 ds_read
//   -> stage t+2 (6 gload16 -> slot t-1) -> setprio(1) 32 MFMA.
// Last tile vmcnt(0) (r3/r4). vmcnt BEFORE barrier (r7). WAR: slot t-1's
// reads all preceded bar(t). Swizzle (r9 pair, 0 conflicts): store chunk
// (tid&3)^((tid>>3)&3) [key (srow>>1)&3], read chunk g at slot g^((lr>>1)&3)
// [mi*16/wr*128 vanish in bits 1:2]. Work order: nt fastest in XCD chunk.
template <int KD, int KSPL, int NTP, bool GATHER, bool SQRELU>
__global__ __launch_bounds__(256, 2) void moe_gemm_kernel(
    const unsigned short* __restrict__ A0, const unsigned short* __restrict__ B0,
    const int* __restrict__ counts,
    const int* __restrict__ pair_token, const float* __restrict__ pair_w,
    unsigned short* __restrict__ h1out, float* __restrict__ out) {
  constexpr int ND = SQRELU ? FFDIM : HDIM;
  constexpr int KLEN = KD / KSPL;
  constexpr int NTILES = KLEN / 32;

  // XCD-chunked bijective swizzle (gridDim.x % 8 == 0); nt fastest
  int d = blockIdx.x;
  int nb = gridDim.x;
  int w = (d & 7) * (nb >> 3) + (d >> 3);
  int nt = w % NTP;
  int rest = w / NTP;
  int ks = rest % KSPL;
  int mt = rest / KSPL;

  // ---- expert-tile search (wave-uniform), 256-row tiles ----
  int eSel = -1, tloc = 0, segstart = 0, segcnt = 0;
  {
    int cumt = 0, acc = 0;
#pragma unroll
    for (int ee = 0; ee < NEXP; ee++) {
      int c = counts[ee];
      int ntl = (c + 255) >> 8;
      if (eSel < 0 && mt < cumt + ntl) { eSel = ee; tloc = mt - cumt; segstart = acc; segcnt = c; }
      cumt += ntl; acc += c;
    }
  }
  if (eSel < 0) return;

  const unsigned short* B = B0 + (size_t)eSel * ND * KD + (size_t)ks * KLEN;
  const unsigned short* Abase = A0 + (size_t)ks * KLEN;

  int tid = threadIdx.x;
  int lane = tid & 63;
  int wv = tid >> 6;       // 0..3
  int wr = wv >> 1;        // 0..1  (M: rows wr*128..+127)
  int wc = wv & 1;         // 0..1  (N: cols wc*64..+63)
  int g  = lane >> 4;      // 0..3
  int lr = lane & 15;

  // staging: A issue r covers rows r*64 + srow (r=0..3); B issue r (r=0..1)
  int srow = tid >> 2;                       // 0..63
  int schunk = (tid & 3) ^ ((tid >> 3) & 3); // pre-swizzled source chunk
  const unsigned short* aP[4];
  const unsigned short* bP[2];
#pragma unroll
  for (int r = 0; r < 4; r++) {
    int idx = tloc * 256 + r * 64 + srow;
    if (idx >= segcnt) idx = segcnt - 1;     // clamp pad rows
    int p = segstart + idx;
    size_t rowoff;
    if (GATHER) rowoff = (size_t)pair_token[p] * KD;
    else        rowoff = (size_t)p * KD;
    aP[r] = Abase + rowoff + schunk * 8;
  }
#pragma unroll
  for (int r = 0; r < 2; r++)
    bP[r] = B + (size_t)(nt * 128 + r * 64 + srow) * KD + schunk * 8;

  __shared__ char lds[73728];          // 3 slots x (A 16KB + B 8KB)
  const char* ldsc = lds;
  int ldsW = wv * 1024;                // wave-uniform (lane*16 added by HW)

  f32x4 acc[8][4];
#pragma unroll
  for (int i = 0; i < 8; i++)
#pragma unroll
    for (int j = 0; j < 4; j++) acc[i][j] = (f32x4){0.f, 0.f, 0.f, 0.f};

  // per-thread LDS read bases (within a slot)
  int swz = (g ^ ((lr >> 1) & 3)) * 16;
  int abase0 = (wr * 128 + lr) * 64 + swz;           // + mi*1024 (mi 0..7)
  int bbase0 = 16384 + (wc * 64 + lr) * 64 + swz;    // + nj*1024 (nj 0..3)

  // prologue: stage tiles 0 and 1 into slots 0,1 (6 gload16 each)
#pragma unroll
  for (int t = 0; t < 2; t++) {
    int so = t * 24576;
#pragma unroll
    for (int r = 0; r < 4; r++) gload16(aP[r], ldsc + so + r * 4096 + ldsW);
#pragma unroll
    for (int r = 0; r < 2; r++) gload16(bP[r], ldsc + so + 16384 + r * 4096 + ldsW);
#pragma unroll
    for (int r = 0; r < 4; r++) aP[r] += 32;
#pragma unroll
    for (int r = 0; r < 2; r++) bP[r] += 32;
  }

  int rsOff = 0, rs2Off = 49152;
  for (int t = 0; t < NTILES; ++t) {
    // own newest 6 = t+1's loads; everything older (tile t) forced complete.
    if (t < NTILES - 1) {
      asm volatile("s_waitcnt vmcnt(6)" ::: "memory");
    } else {
      asm volatile("s_waitcnt vmcnt(0)" ::: "memory");
    }
    __builtin_amdgcn_s_barrier();
    __builtin_amdgcn_sched_barrier(0);

    short8 af[8], bf[4];
#pragma unroll
    for (int mi = 0; mi < 8; mi++)
      af[mi] = *(const short8*)(ldsc + rsOff + abase0 + mi * 1024);
#pragma unroll
    for (int nj = 0; nj < 4; nj++)
      bf[nj] = *(const short8*)(ldsc + rsOff + bbase0 + nj * 1024);

    if (t + 2 < NTILES) {              // stage tile t+2 into slot of tile t-1
#pragma unroll
      for (int r = 0; r < 4; r++) gload16(aP[r], ldsc + rs2Off + r * 4096 + ldsW);
#pragma unroll
      for (int r = 0; r < 2; r++) gload16(bP[r], ldsc + rs2Off + 16384 + r * 4096 + ldsW);
#pragma unroll
      for (int r = 0; r < 4; r++) aP[r] += 32;
#pragma unroll
      for (int r = 0; r < 2; r++) bP[r] += 32;
    }

    __builtin_amdgcn_s_setprio(1);
#pragma unroll
    for (int mi = 0; mi < 8; mi++)
#pragma unroll
      for (int nj = 0; nj < 4; nj++)
        acc[mi][nj] = __builtin_amdgcn_mfma_f32_16x16x32_bf16(af[mi], bf[nj], acc[mi][nj], 0, 0, 0);
    __builtin_amdgcn_s_setprio(0);

    rsOff  = (rsOff  == 49152) ? 0 : rsOff  + 24576;
    rs2Off = (rs2Off == 49152) ? 0 : rs2Off + 24576;
  }

  // ---- epilogue: C/D layout col=lane&15, row=(lane>>4)*4+q ----
  int colb = nt * 128 + wc * 64 + lr;        // + nj*16
  int rowb = tloc * 256 + wr * 128 + g * 4;  // + mi*16 + q
#pragma unroll
  for (int mi = 0; mi < 8; mi++) {
#pragma unroll
    for (int q = 0; q < 4; q++) {
      int idx = rowb + mi * 16 + q;
      if (idx < segcnt) {
        int p = segstart + idx;
        if (SQRELU) {
          size_t ro = (size_t)p * FFDIM + colb;
#pragma unroll
          for (int nj = 0; nj < 4; nj++) {
            float v = acc[mi][nj][q];
            v = v > 0.f ? v * v : 0.f;
            h1out[ro + nj * 16] = f2bf(v);
          }
        } else {
          int tok = pair_token[p];
          float wgt = pair_w[p];
          size_t ro = (size_t)tok * HDIM + colb;
#pragma unroll
          for (int nj = 0; nj < 4; nj++)
            atomicAdd(out + ro + nj * 16, acc[mi][nj][q] * wgt);
        }
      }
    }
  }
}

// ---------------- launch ----------------

extern "C" void kernel_launch(void* const* d_in, const int* in_sizes, int n_in,
                              void* d_out, int out_size, void* d_ws, size_t ws_size,
                              hipStream_t stream) {
  (void)in_sizes; (void)n_in; (void)out_size; (void)ws_size;
  const float* x     = (const float*)d_in[0];
  const float* Wg    = (const float*)d_in[1];
  const float* Wfc   = (const float*)d_in[2];
  const float* Wproj = (const float*)d_in[3];
  float* out = (float*)d_out;

  char* w = (char*)d_ws;
  size_t o = 0;
  auto take = [&](size_t n) { char* p = w + o; o += (n + 255) & ~(size_t)255; return p; };
  unsigned short* xb     = (unsigned short*)take((size_t)T_TOK * HDIM * 2);
  unsigned short* WfcT   = (unsigned short*)take((size_t)NEXP * FFDIM * HDIM * 2);
  unsigned short* WprojT = (unsigned short*)take((size_t)NEXP * HDIM * FFDIM * 2);
  unsigned short* h1     = (unsigned short*)take((size_t)NPAIR * FFDIM * 2);
  int*   sel_e      = (int*)take(T_TOK * 2 * 4);
  float* sel_w      = (float*)take(T_TOK * 2 * 4);
  int*   pair_token = (int*)take(NPAIR * 4);
  float* pair_w     = (float*)take(NPAIR * 4);
  int*   counts     = (int*)take(3 * 8 * 4);
  int*   offsets    = counts + 8;
  int*   cursor     = counts + 16;

  hipMemsetAsync(out, 0, (size_t)T_TOK * HDIM * 4, stream);
  hipMemsetAsync(counts, 0, 96, stream);

  router_kernel<<<T_TOK / 4, 256, 0, stream>>>(x, Wg, xb, sel_e, sel_w, counts);
  transpose_bf16_kernel<<<dim3(FFDIM / 64, HDIM / 256, NEXP), 256, 0, stream>>>(Wfc, WfcT, HDIM, FFDIM);
  transpose_bf16_kernel<<<dim3(HDIM / 64, FFDIM / 256, NEXP), 256, 0, stream>>>(Wproj, WprojT, FFDIM, HDIM);
  offsets_kernel<<<1, 64, 0, stream>>>(counts, offsets, cursor);
  scatter_kernel<<<T_TOK / 256, 256, 0, stream>>>(sel_e, sel_w, cursor, pair_token, pair_w);

  // GEMM1: per expert, [seg x 1024] x [1024 x 4096] -> relu^2 -> h1 (bf16)
  moe_gemm_kernel<HDIM, 1, FFDIM / 128, true, true>
      <<<(FFDIM / 128) * MAXMT, 256, 0, stream>>>(xb, WfcT, counts,
                                                  pair_token, pair_w, h1, nullptr);
  // GEMM2: per expert, [seg x 4096] x [4096 x 1024] -> weighted combine, split-K=2
  moe_gemm_kernel<FFDIM, 2, HDIM / 128, false, false>
      <<<(HDIM / 128) * 2 * MAXMT, 256, 0, stream>>>(h1, WprojT, counts,
                                                     pair_token, pair_w, nullptr, out);
}

// Round 16
// 422.820 us; speedup vs baseline: 1.0656x; 1.0656x over previous
//
#include <hip/hip_runtime.h>

#define T_TOK 4096
#define HDIM  1024
#define NEXP  8
#define FFDIM 4096
#define NPAIR 8192   // T_TOK * topk
#define MAXMT 72     // max total 128-row M-tiles across experts: 8192/128 + 8

typedef __attribute__((ext_vector_type(8))) short short8;
typedef __attribute__((ext_vector_type(8))) unsigned short ushort8;
typedef __attribute__((ext_vector_type(4))) unsigned short ushort4_t;
typedef __attribute__((ext_vector_type(4))) float f32x4;

__device__ __forceinline__ unsigned short f2bf(float f) {
  unsigned int u = __float_as_uint(f);
  u += 0x7fffu + ((u >> 16) & 1u);   // RNE
  return (unsigned short)(u >> 16);
}
__device__ __forceinline__ float bf2f(unsigned short u) {
  return __uint_as_float((unsigned int)u << 16);
}

// global -> LDS direct copy, 16B per lane. LDS dest is wave-uniform base;
// HW writes lane l at base + l*16. Global source address is per-lane.
__device__ __forceinline__ void gload16(const void* g, const void* l) {
  __builtin_amdgcn_global_load_lds(
      (const __attribute__((address_space(1))) unsigned int*)(unsigned long long)g,
      (__attribute__((address_space(3))) unsigned int*)(unsigned int)(unsigned long long)l,
      16, 0, 0);
}

// ---------------- transpose v2 (r14, kept) ----------------
__global__ __launch_bounds__(256) void transpose_bf16_kernel(
    const float* __restrict__ in, unsigned short* __restrict__ out, int M, int N) {
  in  += (size_t)blockIdx.z * M * N;
  out += (size_t)blockIdx.z * M * N;
  __shared__ unsigned short t[64][264];
  int tid = threadIdx.x;
  int r0 = blockIdx.y * 256, c0 = blockIdx.x * 64;
  int colb = (tid & 15) * 4;
  int rowi = tid >> 4;
  int sw = (tid & 7) << 3;
#pragma unroll
  for (int i = 0; i < 16; i++) {
    int row = i * 16 + rowi;
    float4 v = *(const float4*)(in + (size_t)(r0 + row) * N + c0 + colb);
    int rs = row ^ sw;
    t[colb + 0][rs] = f2bf(v.x);
    t[colb + 1][rs] = f2bf(v.y);
    t[colb + 2][rs] = f2bf(v.z);
    t[colb + 3][rs] = f2bf(v.w);
  }
  __syncthreads();
  int m0 = (tid & 31) * 8;
  int nsub = tid >> 5;
#pragma unroll
  for (int i = 0; i < 8; i++) {
    int n = i * 8 + nsub;
    int sn = ((n >> 2) & 7) << 3;
    ushort8 v = *(const ushort8*)&t[n][m0 ^ sn];
    *(ushort8*)(out + (size_t)(c0 + n) * M + r0 + m0) = v;
  }
}

// ---------------- router (fused: also emits bf16 x) ----------------

__global__ __launch_bounds__(256) void router_kernel(
    const float* __restrict__ x, const float* __restrict__ wg,
    unsigned short* __restrict__ xb,
    int* __restrict__ sel_e, float* __restrict__ sel_w, int* __restrict__ counts) {
  int lane = threadIdx.x & 63;
  int t = blockIdx.x * 4 + (threadIdx.x >> 6);
  const float* xr = x + (size_t)t * HDIM;
  unsigned short* xo = xb + (size_t)t * HDIM;
  float acc[8] = {0, 0, 0, 0, 0, 0, 0, 0};
  for (int i = 0; i < HDIM / 64; i++) {
    int h = i * 64 + lane;
    float xv = xr[h];
    xo[h] = f2bf(xv);                        // fused convert_x
    float4 w0 = *(const float4*)(wg + h * 8);
    float4 w1 = *(const float4*)(wg + h * 8 + 4);
    acc[0] += xv * w0.x; acc[1] += xv * w0.y; acc[2] += xv * w0.z; acc[3] += xv * w0.w;
    acc[4] += xv * w1.x; acc[5] += xv * w1.y; acc[6] += xv * w1.z; acc[7] += xv * w1.w;
  }
#pragma unroll
  for (int off = 32; off > 0; off >>= 1) {
#pragma unroll
    for (int e = 0; e < 8; e++) acc[e] += __shfl_xor(acc[e], off, 64);
  }
  if (lane == 0) {
    int e0 = 0; float b0 = acc[0];
#pragma unroll
    for (int e = 1; e < 8; e++) if (acc[e] > b0) { b0 = acc[e]; e0 = e; }
    int e1 = -1; float b1 = -3.4e38f;
#pragma unroll
    for (int e = 0; e < 8; e++) if (e != e0 && acc[e] > b1) { b1 = acc[e]; e1 = e; }
    float q = expf(b1 - b0);                 // softmax denominator cancels in renorm
    float w0 = 1.0f / (1.0f + q);
    float w1 = q / (1.0f + q);
    sel_e[t * 2] = e0; sel_e[t * 2 + 1] = e1;
    sel_w[t * 2] = w0; sel_w[t * 2 + 1] = w1;
    atomicAdd(&counts[e0], 1);
    atomicAdd(&counts[e1], 1);
  }
}

__global__ void offsets_kernel(const int* __restrict__ counts,
                               int* __restrict__ offsets, int* __restrict__ cursor) {
  if (threadIdx.x == 0 && blockIdx.x == 0) {
    int s = 0;
    for (int e = 0; e < NEXP; e++) { offsets[e] = s; cursor[e] = s; s += counts[e]; }
  }
}

__global__ __launch_bounds__(256) void scatter_kernel(
    const int* __restrict__ sel_e,
    int* __restrict__ cursor, int* __restrict__ pair_token, int* __restrict__ pair_pos) {
  int t = blockIdx.x * 256 + threadIdx.x;
#pragma unroll
  for (int j = 0; j < 2; j++) {
    int e = sel_e[t * 2 + j];
    int pos = atomicAdd(&cursor[e], 1);
    pair_token[pos] = t;
    pair_pos[t * 2 + j] = pos;
  }
}

// ---------------- combine: out[t] = sum_j w_j * (y0[pos_j] + y1[pos_j]) ----------------
__global__ __launch_bounds__(256) void combine_kernel(
    const unsigned short* __restrict__ y,   // [2][NPAIR][HDIM] bf16 split-K partials
    const int* __restrict__ pair_pos, const float* __restrict__ sel_w,
    float* __restrict__ out) {
  int i = blockIdx.x * 256 + threadIdx.x;   // over T_TOK * (HDIM/8)
  int t = i >> 7;
  int c = (i & 127) * 8;
  int p0 = pair_pos[t * 2], p1 = pair_pos[t * 2 + 1];
  float w0 = sel_w[t * 2], w1 = sel_w[t * 2 + 1];
  const unsigned short* y1p = y + (size_t)NPAIR * HDIM;
  ushort8 a0 = *(const ushort8*)(y + (size_t)p0 * HDIM + c);
  ushort8 b0 = *(const ushort8*)(y1p + (size_t)p0 * HDIM + c);
  ushort8 a1 = *(const ushort8*)(y + (size_t)p1 * HDIM + c);
  ushort8 b1 = *(const ushort8*)(y1p + (size_t)p1 * HDIM + c);
  float r[8];
#pragma unroll
  for (int j = 0; j < 8; j++)
    r[j] = w0 * (bf2f(a0[j]) + bf2f(b0[j])) + w1 * (bf2f(a1[j]) + bf2f(b1[j]));
  float4 v0 = {r[0], r[1], r[2], r[3]};
  float4 v1 = {r[4], r[5], r[6], r[7]};
  float* op = out + (size_t)t * HDIM + c;
  *(float4*)op = v0;
  *(float4*)(op + 4) = v1;
}

// --- expert GEMMs: r13 loop (best measured) + coalesced LDS-bounce epilogue ---
// 128x256 tile, BK=32, 3-slot ring (72KB), 8 waves (2M x 4N), wave tile 64x64,
// acc[4][4]. Per K-tile: vmcnt(3) -> s_barrier -> 8 ds_read(slot t) -> stage
// t+2 (3 gload16 -> slot t-1) -> setprio(1) 16 MFMA. Last tile vmcnt(0) (r3/r4);
// vmcnt BEFORE barrier (r7); WAR: slot t-1's reads preceded bar(t). Swizzle
// (r2/r9 pair, 0 conflicts). Work order: nt fastest in XCD chunk.
// EPILOGUE (new): old one did 64 scalar stride-16 ushort stores/thread (~25us);
// GEMM2 additionally 16.8M atomic f32 adds. Now: bounce the 128x256 bf16 tile
// through LDS (pitch 260 ushorts: write banks (row*130+(col>>1))&31 -> g adds
// 8g {0,8,16,24}, lr pairs 8 banks = 32 distinct 2-way-free; 520B rows keep 8B
// align for b64) then store ushort4 row-major, coalesced. GEMM2 (SQRELU=0)
// writes UNWEIGHTED split-K partials to y[ks][pair][HDIM]; combine applies
// weights -> zero atomics.
template <int KD, int KSPL, int NTP, bool GATHER, bool SQRELU>
__global__ __launch_bounds__(512, 4) void moe_gemm_kernel(
    const unsigned short* __restrict__ A0, const unsigned short* __restrict__ B0,
    const int* __restrict__ counts, const int* __restrict__ pair_token,
    unsigned short* __restrict__ Cout) {
  constexpr int ND = SQRELU ? FFDIM : HDIM;
  constexpr int KLEN = KD / KSPL;
  constexpr int NTILES = KLEN / 32;

  // XCD-chunked bijective swizzle (gridDim.x % 8 == 0); nt fastest
  int d = blockIdx.x;
  int nb = gridDim.x;
  int w = (d & 7) * (nb >> 3) + (d >> 3);
  int nt = w % NTP;
  int rest = w / NTP;
  int ks = rest % KSPL;
  int mt = rest / KSPL;

  // ---- expert-tile search (wave-uniform) ----
  int eSel = -1, tloc = 0, segstart = 0, segcnt = 0;
  {
    int cumt = 0, acc = 0;
#pragma unroll
    for (int ee = 0; ee < NEXP; ee++) {
      int c = counts[ee];
      int ntl = (c + 127) >> 7;
      if (eSel < 0 && mt < cumt + ntl) { eSel = ee; tloc = mt - cumt; segstart = acc; segcnt = c; }
      cumt += ntl; acc += c;
    }
  }
  if (eSel < 0) return;

  if (!SQRELU) Cout += (size_t)ks * NPAIR * HDIM;   // split-K partial buffer

  const unsigned short* B = B0 + (size_t)eSel * ND * KD + (size_t)ks * KLEN;
  const unsigned short* Abase = A0 + (size_t)ks * KLEN;

  int tid = threadIdx.x;
  int lane = tid & 63;
  int wv = tid >> 6;       // 0..7
  int wr = wv >> 2;        // 0..1  (M)
  int wc = wv & 3;         // 0..3  (N)
  int g  = lane >> 4;      // 0..3
  int lr = lane & 15;

  int srow = tid >> 2;                       // 0..127
  int schunk = (tid & 3) ^ ((tid >> 3) & 3); // pre-swizzled source chunk
  const unsigned short* aP;
  const unsigned short* bP[2];
  {
    int idx = tloc * 128 + srow;
    if (idx >= segcnt) idx = segcnt - 1;     // clamp pad rows
    int p = segstart + idx;
    size_t rowoff;
    if (GATHER) rowoff = (size_t)pair_token[p] * KD;
    else        rowoff = (size_t)p * KD;
    aP = Abase + rowoff + schunk * 8;
#pragma unroll
    for (int r = 0; r < 2; r++)
      bP[r] = B + (size_t)(nt * 256 + r * 128 + srow) * KD + schunk * 8;
  }

  __shared__ char lds[73728];          // 3 slots x (A 8KB + B 16KB)
  const char* ldsc = lds;
  int ldsW = wv * 1024;                // wave-uniform (lane*16 added by HW)

  f32x4 acc[4][4];
#pragma unroll
  for (int i = 0; i < 4; i++)
#pragma unroll
    for (int j = 0; j < 4; j++) acc[i][j] = (f32x4){0.f, 0.f, 0.f, 0.f};

  int swz = (g ^ ((lr >> 1) & 3)) * 16;
  int abase0 = (wr * 64 + lr) * 64 + swz;            // + mi*1024
  int bbase0 = 8192 + (wc * 64 + lr) * 64 + swz;     // + nj*1024

  // prologue: stage tiles 0 and 1 into slots 0,1
#pragma unroll
  for (int t = 0; t < 2; t++) {
    int so = t * 24576;
    gload16(aP, ldsc + so + ldsW);
    gload16(bP[0], ldsc + so + 8192 + ldsW);
    gload16(bP[1], ldsc + so + 16384 + ldsW);
    aP += 32; bP[0] += 32; bP[1] += 32;
  }

  int rsOff = 0, rs2Off = 49152;
  for (int t = 0; t < NTILES; ++t) {
    if (t < NTILES - 1) {
      asm volatile("s_waitcnt vmcnt(3)" ::: "memory");
    } else {
      asm volatile("s_waitcnt vmcnt(0)" ::: "memory");
    }
    __builtin_amdgcn_s_barrier();
    __builtin_amdgcn_sched_barrier(0);

    short8 af[4], bf[4];
#pragma unroll
    for (int mi = 0; mi < 4; mi++)
      af[mi] = *(const short8*)(ldsc + rsOff + abase0 + mi * 1024);
#pragma unroll
    for (int nj = 0; nj < 4; nj++)
      bf[nj] = *(const short8*)(ldsc + rsOff + bbase0 + nj * 1024);

    if (t + 2 < NTILES) {              // stage tile t+2 into slot of tile t-1
      gload16(aP, ldsc + rs2Off + ldsW);
      gload16(bP[0], ldsc + rs2Off + 8192 + ldsW);
      gload16(bP[1], ldsc + rs2Off + 16384 + ldsW);
      aP += 32; bP[0] += 32; bP[1] += 32;
    }

    __builtin_amdgcn_s_setprio(1);
#pragma unroll
    for (int mi = 0; mi < 4; mi++)
#pragma unroll
      for (int nj = 0; nj < 4; nj++)
        acc[mi][nj] = __builtin_amdgcn_mfma_f32_16x16x32_bf16(af[mi], bf[nj], acc[mi][nj], 0, 0, 0);
    __builtin_amdgcn_s_setprio(0);

    rsOff  = (rsOff  == 49152) ? 0 : rsOff  + 24576;
    rs2Off = (rs2Off == 49152) ? 0 : rs2Off + 24576;
  }

  // ---- epilogue: LDS bounce -> coalesced ushort4 stores ----
  // fragment: row = wr*64+mi*16+g*4+q, col = wc*64+nj*16+lr (C/D layout m89)
  __syncthreads();                     // all waves done reading ring slots
  unsigned short* t2 = (unsigned short*)lds;   // [128][260]
#pragma unroll
  for (int mi = 0; mi < 4; mi++) {
#pragma unroll
    for (int q = 0; q < 4; q++) {
      int row = wr * 64 + mi * 16 + g * 4 + q;
#pragma unroll
      for (int nj = 0; nj < 4; nj++) {
        int col = wc * 64 + nj * 16 + lr;
        float v = acc[mi][nj][q];
        if (SQRELU) v = v > 0.f ? v * v : 0.f;
        t2[row * 260 + col] = f2bf(v);
      }
    }
  }
  __syncthreads();
  {
    int row = tid >> 2;                // 0..127
    int idx = tloc * 128 + row;
    if (idx < segcnt) {
      size_t base = (size_t)(segstart + idx) * ND + nt * 256;
      const unsigned short* src = t2 + row * 260;
#pragma unroll
      for (int i = 0; i < 16; i++) {
        int c = ((tid & 3) + i * 4) * 4;
        *(ushort4_t*)(Cout + base + c) = *(const ushort4_t*)(src + c);
      }
    }
  }
}

// ---------------- launch ----------------

extern "C" void kernel_launch(void* const* d_in, const int* in_sizes, int n_in,
                              void* d_out, int out_size, void* d_ws, size_t ws_size,
                              hipStream_t stream) {
  (void)in_sizes; (void)n_in; (void)out_size; (void)ws_size;
  const float* x     = (const float*)d_in[0];
  const float* Wg    = (const float*)d_in[1];
  const float* Wfc   = (const float*)d_in[2];
  const float* Wproj = (const float*)d_in[3];
  float* out = (float*)d_out;

  char* w = (char*)d_ws;
  size_t o = 0;
  auto take = [&](size_t n) { char* p = w + o; o += (n + 255) & ~(size_t)255; return p; };
  unsigned short* xb     = (unsigned short*)take((size_t)T_TOK * HDIM * 2);
  unsigned short* WfcT   = (unsigned short*)take((size_t)NEXP * FFDIM * HDIM * 2);
  unsigned short* WprojT = (unsigned short*)take((size_t)NEXP * HDIM * FFDIM * 2);
  unsigned short* h1     = (unsigned short*)take((size_t)NPAIR * FFDIM * 2);
  unsigned short* y      = (unsigned short*)take((size_t)2 * NPAIR * HDIM * 2);
  int*   sel_e      = (int*)take(T_TOK * 2 * 4);
  float* sel_w      = (float*)take(T_TOK * 2 * 4);
  int*   pair_token = (int*)take(NPAIR * 4);
  int*   pair_pos   = (int*)take(NPAIR * 4);
  int*   counts     = (int*)take(3 * 8 * 4);
  int*   offsets    = counts + 8;
  int*   cursor     = counts + 16;

  hipMemsetAsync(counts, 0, 96, stream);

  router_kernel<<<T_TOK / 4, 256, 0, stream>>>(x, Wg, xb, sel_e, sel_w, counts);
  transpose_bf16_kernel<<<dim3(FFDIM / 64, HDIM / 256, NEXP), 256, 0, stream>>>(Wfc, WfcT, HDIM, FFDIM);
  transpose_bf16_kernel<<<dim3(HDIM / 64, FFDIM / 256, NEXP), 256, 0, stream>>>(Wproj, WprojT, FFDIM, HDIM);
  offsets_kernel<<<1, 64, 0, stream>>>(counts, offsets, cursor);
  scatter_kernel<<<T_TOK / 256, 256, 0, stream>>>(sel_e, cursor, pair_token, pair_pos);

  // GEMM1: per expert, [seg x 1024] x [1024 x 4096] -> relu^2 -> h1 (bf16)
  moe_gemm_kernel<HDIM, 1, FFDIM / 256, true, true>
      <<<(FFDIM / 256) * MAXMT, 512, 0, stream>>>(xb, WfcT, counts, pair_token, h1);
  // GEMM2: per expert, [seg x 4096] x [4096 x 1024] -> split-K=2 partials y (no atomics)
  moe_gemm_kernel<FFDIM, 2, HDIM / 256, false, false>
      <<<(HDIM / 256) * 2 * MAXMT, 512, 0, stream>>>(h1, WprojT, counts, pair_token, y);
  // combine: out[t] = w0*(y0[pos0]+y1[pos0]) + w1*(y0[pos1]+y1[pos1])
  combine_kernel<<<T_TOK * (HDIM / 8) / 256, 256, 0, stream>>>(y, pair_pos, sel_w, out);
}

// Round 17
// 413.001 us; speedup vs baseline: 1.0910x; 1.0238x over previous
//
#include <hip/hip_runtime.h>

#define T_TOK 4096
#define HDIM  1024
#define NEXP  8
#define FFDIM 4096
#define NPAIR 8192   // T_TOK * topk
#define MAXMT 72     // max total 128-row M-tiles across experts: 8192/128 + 8

typedef __attribute__((ext_vector_type(8))) short short8;
typedef __attribute__((ext_vector_type(8))) unsigned short ushort8;
typedef __attribute__((ext_vector_type(4))) unsigned short ushort4_t;
typedef __attribute__((ext_vector_type(4))) float f32x4;

__device__ __forceinline__ unsigned short f2bf(float f) {
  unsigned int u = __float_as_uint(f);
  u += 0x7fffu + ((u >> 16) & 1u);   // RNE
  return (unsigned short)(u >> 16);
}
__device__ __forceinline__ float bf2f(unsigned short u) {
  return __uint_as_float((unsigned int)u << 16);
}

// global -> LDS direct copy, 16B per lane. LDS dest is wave-uniform base;
// HW writes lane l at base + l*16. Global source address is per-lane.
__device__ __forceinline__ void gload16(const void* g, const void* l) {
  __builtin_amdgcn_global_load_lds(
      (const __attribute__((address_space(1))) unsigned int*)(unsigned long long)g,
      (__attribute__((address_space(3))) unsigned int*)(unsigned int)(unsigned long long)l,
      16, 0, 0);
}

// ---------------- fused transpose v3 ----------------
// Both weights in ONE launch (flat grid: id<2048 -> Wfc 1024x4096; else Wproj
// 4096x1024). Tile 256M x 64N. v2 did 64 scalar ds_write_b16/thread (classic
// one-side-scalar transpose, LDS-issue bound). v3: 4x4 register micro-transpose
// -> 4 float4 reads + 4 ds_write_b64 per micro (24 LDS issues/thread vs 72).
// Rows padded to 264 ushorts (528B): b64 writes 8B-aligned; ushort8 reads 16B
// aligned + CONTIGUOUS across lanes (32 lanes x 16B = one 512B row span, all
// banks, conflict-free). Write conflicts <=4-way on a minority op.
__global__ __launch_bounds__(256) void fused_transpose_kernel(
    const float* __restrict__ Wfc, unsigned short* __restrict__ WfcT,
    const float* __restrict__ Wproj, unsigned short* __restrict__ WprojT) {
  int id = blockIdx.x;
  const float* in; unsigned short* out; int M, N, my, nx, e;
  if (id < 2048) {
    in = Wfc; out = WfcT; M = 1024; N = 4096;
    e = id >> 8; int r = id & 255; my = r >> 6; nx = r & 63;
  } else {
    in = Wproj; out = WprojT; M = 4096; N = 1024;
    int b = id - 2048; e = b >> 8; int r = b & 255; my = r >> 4; nx = r & 15;
  }
  in  += (size_t)e * M * N;
  out += (size_t)e * M * N;
  __shared__ unsigned short t[64 * 264];
  int tid = threadIdx.x;
  int r0 = my * 256, c0 = nx * 64;
  int nc = tid & 15, mrb = tid >> 4;
#pragma unroll
  for (int p = 0; p < 4; p++) {
    int m = (p * 16 + mrb) * 4;
    int c = nc * 4;
    const float* src = in + (size_t)(r0 + m) * N + c0 + c;
    float4 v0 = *(const float4*)(src);
    float4 v1 = *(const float4*)(src + N);
    float4 v2 = *(const float4*)(src + 2 * (size_t)N);
    float4 v3 = *(const float4*)(src + 3 * (size_t)N);
    ushort4_t w0 = {f2bf(v0.x), f2bf(v1.x), f2bf(v2.x), f2bf(v3.x)};
    ushort4_t w1 = {f2bf(v0.y), f2bf(v1.y), f2bf(v2.y), f2bf(v3.y)};
    ushort4_t w2 = {f2bf(v0.z), f2bf(v1.z), f2bf(v2.z), f2bf(v3.z)};
    ushort4_t w3 = {f2bf(v0.w), f2bf(v1.w), f2bf(v2.w), f2bf(v3.w)};
    *(ushort4_t*)&t[(c + 0) * 264 + m] = w0;
    *(ushort4_t*)&t[(c + 1) * 264 + m] = w1;
    *(ushort4_t*)&t[(c + 2) * 264 + m] = w2;
    *(ushort4_t*)&t[(c + 3) * 264 + m] = w3;
  }
  __syncthreads();
  int m0 = (tid & 31) * 8;
  int nsub = tid >> 5;
#pragma unroll
  for (int i = 0; i < 8; i++) {
    int n = i * 8 + nsub;
    ushort8 v = *(const ushort8*)&t[n * 264 + m0];
    *(ushort8*)(out + (size_t)(c0 + n) * M + r0 + m0) = v;
  }
}

// ---------------- router (fused: also emits bf16 x) ----------------

__global__ __launch_bounds__(256) void router_kernel(
    const float* __restrict__ x, const float* __restrict__ wg,
    unsigned short* __restrict__ xb,
    int* __restrict__ sel_e, float* __restrict__ sel_w, int* __restrict__ counts) {
  int lane = threadIdx.x & 63;
  int t = blockIdx.x * 4 + (threadIdx.x >> 6);
  const float* xr = x + (size_t)t * HDIM;
  unsigned short* xo = xb + (size_t)t * HDIM;
  float acc[8] = {0, 0, 0, 0, 0, 0, 0, 0};
  for (int i = 0; i < HDIM / 64; i++) {
    int h = i * 64 + lane;
    float xv = xr[h];
    xo[h] = f2bf(xv);                        // fused convert_x
    float4 w0 = *(const float4*)(wg + h * 8);
    float4 w1 = *(const float4*)(wg + h * 8 + 4);
    acc[0] += xv * w0.x; acc[1] += xv * w0.y; acc[2] += xv * w0.z; acc[3] += xv * w0.w;
    acc[4] += xv * w1.x; acc[5] += xv * w1.y; acc[6] += xv * w1.z; acc[7] += xv * w1.w;
  }
#pragma unroll
  for (int off = 32; off > 0; off >>= 1) {
#pragma unroll
    for (int e = 0; e < 8; e++) acc[e] += __shfl_xor(acc[e], off, 64);
  }
  if (lane == 0) {
    int e0 = 0; float b0 = acc[0];
#pragma unroll
    for (int e = 1; e < 8; e++) if (acc[e] > b0) { b0 = acc[e]; e0 = e; }
    int e1 = -1; float b1 = -3.4e38f;
#pragma unroll
    for (int e = 0; e < 8; e++) if (e != e0 && acc[e] > b1) { b1 = acc[e]; e1 = e; }
    float q = expf(b1 - b0);                 // softmax denominator cancels in renorm
    float w0 = 1.0f / (1.0f + q);
    float w1 = q / (1.0f + q);
    sel_e[t * 2] = e0; sel_e[t * 2 + 1] = e1;
    sel_w[t * 2] = w0; sel_w[t * 2 + 1] = w1;
    atomicAdd(&counts[e0], 1);
    atomicAdd(&counts[e1], 1);
  }
}

// ---------------- scatter (offsets computed inline; offsets_kernel removed) ----------------

__global__ __launch_bounds__(256) void scatter_kernel(
    const int* __restrict__ counts, const int* __restrict__ sel_e,
    int* __restrict__ cursor, int* __restrict__ pair_token, int* __restrict__ pair_pos) {
  int t = blockIdx.x * 256 + threadIdx.x;
  int offs[NEXP];
  {
    int s = 0;
#pragma unroll
    for (int e = 0; e < NEXP; e++) { offs[e] = s; s += counts[e]; }
  }
#pragma unroll
  for (int j = 0; j < 2; j++) {
    int e = sel_e[t * 2 + j];
    int pos = offs[e] + atomicAdd(&cursor[e], 1);   // cursor zero-initialized
    pair_token[pos] = t;
    pair_pos[t * 2 + j] = pos;
  }
}

// ---------------- combine: out[t] = sum_j w_j * (y0[pos_j] + y1[pos_j]) ----------------
__global__ __launch_bounds__(256) void combine_kernel(
    const unsigned short* __restrict__ y,   // [2][NPAIR][HDIM] bf16 split-K partials
    const int* __restrict__ pair_pos, const float* __restrict__ sel_w,
    float* __restrict__ out) {
  int i = blockIdx.x * 256 + threadIdx.x;   // over T_TOK * (HDIM/8)
  int t = i >> 7;
  int c = (i & 127) * 8;
  int p0 = pair_pos[t * 2], p1 = pair_pos[t * 2 + 1];
  float w0 = sel_w[t * 2], w1 = sel_w[t * 2 + 1];
  const unsigned short* y1p = y + (size_t)NPAIR * HDIM;
  ushort8 a0 = *(const ushort8*)(y + (size_t)p0 * HDIM + c);
  ushort8 b0 = *(const ushort8*)(y1p + (size_t)p0 * HDIM + c);
  ushort8 a1 = *(const ushort8*)(y + (size_t)p1 * HDIM + c);
  ushort8 b1 = *(const ushort8*)(y1p + (size_t)p1 * HDIM + c);
  float r[8];
#pragma unroll
  for (int j = 0; j < 8; j++)
    r[j] = w0 * (bf2f(a0[j]) + bf2f(b0[j])) + w1 * (bf2f(a1[j]) + bf2f(b1[j]));
  float4 v0 = {r[0], r[1], r[2], r[3]};
  float4 v1 = {r[4], r[5], r[6], r[7]};
  float* op = out + (size_t)t * HDIM + c;
  *(float4*)op = v0;
  *(float4*)(op + 4) = v1;
}

// --- expert GEMMs: r13 loop + r16 coalesced LDS-bounce epilogue (frozen) ---
// 128x256 tile, BK=32, 3-slot ring (72KB), 8 waves (2M x 4N), wave tile 64x64,
// acc[4][4]. Per K-tile: vmcnt(3) -> s_barrier -> 8 ds_read(slot t) -> stage
// t+2 (3 gload16 -> slot t-1) -> setprio(1) 16 MFMA. Last tile vmcnt(0) (r3/r4);
// vmcnt BEFORE barrier (r7); WAR: slot t-1's reads preceded bar(t). Swizzle
// (r2/r9 pair, 0 conflicts). Work order: nt fastest in XCD chunk. Epilogue:
// LDS bounce (pitch 260) -> coalesced ushort4 stores. GEMM2 writes UNWEIGHTED
// split-K partials to y[ks][pair][HDIM]; combine applies weights (no atomics).
template <int KD, int KSPL, int NTP, bool GATHER, bool SQRELU>
__global__ __launch_bounds__(512, 4) void moe_gemm_kernel(
    const unsigned short* __restrict__ A0, const unsigned short* __restrict__ B0,
    const int* __restrict__ counts, const int* __restrict__ pair_token,
    unsigned short* __restrict__ Cout) {
  constexpr int ND = SQRELU ? FFDIM : HDIM;
  constexpr int KLEN = KD / KSPL;
  constexpr int NTILES = KLEN / 32;

  // XCD-chunked bijective swizzle (gridDim.x % 8 == 0); nt fastest
  int d = blockIdx.x;
  int nb = gridDim.x;
  int w = (d & 7) * (nb >> 3) + (d >> 3);
  int nt = w % NTP;
  int rest = w / NTP;
  int ks = rest % KSPL;
  int mt = rest / KSPL;

  // ---- expert-tile search (wave-uniform) ----
  int eSel = -1, tloc = 0, segstart = 0, segcnt = 0;
  {
    int cumt = 0, acc = 0;
#pragma unroll
    for (int ee = 0; ee < NEXP; ee++) {
      int c = counts[ee];
      int ntl = (c + 127) >> 7;
      if (eSel < 0 && mt < cumt + ntl) { eSel = ee; tloc = mt - cumt; segstart = acc; segcnt = c; }
      cumt += ntl; acc += c;
    }
  }
  if (eSel < 0) return;

  if (!SQRELU) Cout += (size_t)ks * NPAIR * HDIM;   // split-K partial buffer

  const unsigned short* B = B0 + (size_t)eSel * ND * KD + (size_t)ks * KLEN;
  const unsigned short* Abase = A0 + (size_t)ks * KLEN;

  int tid = threadIdx.x;
  int lane = tid & 63;
  int wv = tid >> 6;       // 0..7
  int wr = wv >> 2;        // 0..1  (M)
  int wc = wv & 3;         // 0..3  (N)
  int g  = lane >> 4;      // 0..3
  int lr = lane & 15;

  int srow = tid >> 2;                       // 0..127
  int schunk = (tid & 3) ^ ((tid >> 3) & 3); // pre-swizzled source chunk
  const unsigned short* aP;
  const unsigned short* bP[2];
  {
    int idx = tloc * 128 + srow;
    if (idx >= segcnt) idx = segcnt - 1;     // clamp pad rows
    int p = segstart + idx;
    size_t rowoff;
    if (GATHER) rowoff = (size_t)pair_token[p] * KD;
    else        rowoff = (size_t)p * KD;
    aP = Abase + rowoff + schunk * 8;
#pragma unroll
    for (int r = 0; r < 2; r++)
      bP[r] = B + (size_t)(nt * 256 + r * 128 + srow) * KD + schunk * 8;
  }

  __shared__ char lds[73728];          // 3 slots x (A 8KB + B 16KB)
  const char* ldsc = lds;
  int ldsW = wv * 1024;                // wave-uniform (lane*16 added by HW)

  f32x4 acc[4][4];
#pragma unroll
  for (int i = 0; i < 4; i++)
#pragma unroll
    for (int j = 0; j < 4; j++) acc[i][j] = (f32x4){0.f, 0.f, 0.f, 0.f};

  int swz = (g ^ ((lr >> 1) & 3)) * 16;
  int abase0 = (wr * 64 + lr) * 64 + swz;            // + mi*1024
  int bbase0 = 8192 + (wc * 64 + lr) * 64 + swz;     // + nj*1024

  // prologue: stage tiles 0 and 1 into slots 0,1
#pragma unroll
  for (int t = 0; t < 2; t++) {
    int so = t * 24576;
    gload16(aP, ldsc + so + ldsW);
    gload16(bP[0], ldsc + so + 8192 + ldsW);
    gload16(bP[1], ldsc + so + 16384 + ldsW);
    aP += 32; bP[0] += 32; bP[1] += 32;
  }

  int rsOff = 0, rs2Off = 49152;
  for (int t = 0; t < NTILES; ++t) {
    if (t < NTILES - 1) {
      asm volatile("s_waitcnt vmcnt(3)" ::: "memory");
    } else {
      asm volatile("s_waitcnt vmcnt(0)" ::: "memory");
    }
    __builtin_amdgcn_s_barrier();
    __builtin_amdgcn_sched_barrier(0);

    short8 af[4], bf[4];
#pragma unroll
    for (int mi = 0; mi < 4; mi++)
      af[mi] = *(const short8*)(ldsc + rsOff + abase0 + mi * 1024);
#pragma unroll
    for (int nj = 0; nj < 4; nj++)
      bf[nj] = *(const short8*)(ldsc + rsOff + bbase0 + nj * 1024);

    if (t + 2 < NTILES) {              // stage tile t+2 into slot of tile t-1
      gload16(aP, ldsc + rs2Off + ldsW);
      gload16(bP[0], ldsc + rs2Off + 8192 + ldsW);
      gload16(bP[1], ldsc + rs2Off + 16384 + ldsW);
      aP += 32; bP[0] += 32; bP[1] += 32;
    }

    __builtin_amdgcn_s_setprio(1);
#pragma unroll
    for (int mi = 0; mi < 4; mi++)
#pragma unroll
      for (int nj = 0; nj < 4; nj++)
        acc[mi][nj] = __builtin_amdgcn_mfma_f32_16x16x32_bf16(af[mi], bf[nj], acc[mi][nj], 0, 0, 0);
    __builtin_amdgcn_s_setprio(0);

    rsOff  = (rsOff  == 49152) ? 0 : rsOff  + 24576;
    rs2Off = (rs2Off == 49152) ? 0 : rs2Off + 24576;
  }

  // ---- epilogue: LDS bounce -> coalesced ushort4 stores ----
  __syncthreads();                     // all waves done reading ring slots
  unsigned short* t2 = (unsigned short*)lds;   // [128][260]
#pragma unroll
  for (int mi = 0; mi < 4; mi++) {
#pragma unroll
    for (int q = 0; q < 4; q++) {
      int row = wr * 64 + mi * 16 + g * 4 + q;
#pragma unroll
      for (int nj = 0; nj < 4; nj++) {
        int col = wc * 64 + nj * 16 + lr;
        float v = acc[mi][nj][q];
        if (SQRELU) v = v > 0.f ? v * v : 0.f;
        t2[row * 260 + col] = f2bf(v);
      }
    }
  }
  __syncthreads();
  {
    int row = tid >> 2;                // 0..127
    int idx = tloc * 128 + row;
    if (idx < segcnt) {
      size_t base = (size_t)(segstart + idx) * ND + nt * 256;
      const unsigned short* src = t2 + row * 260;
#pragma unroll
      for (int i = 0; i < 16; i++) {
        int c = ((tid & 3) + i * 4) * 4;
        *(ushort4_t*)(Cout + base + c) = *(const ushort4_t*)(src + c);
      }
    }
  }
}

// ---------------- launch ----------------

extern "C" void kernel_launch(void* const* d_in, const int* in_sizes, int n_in,
                              void* d_out, int out_size, void* d_ws, size_t ws_size,
                              hipStream_t stream) {
  (void)in_sizes; (void)n_in; (void)out_size; (void)ws_size;
  const float* x     = (const float*)d_in[0];
  const float* Wg    = (const float*)d_in[1];
  const float* Wfc   = (const float*)d_in[2];
  const float* Wproj = (const float*)d_in[3];
  float* out = (float*)d_out;

  char* w = (char*)d_ws;
  size_t o = 0;
  auto take = [&](size_t n) { char* p = w + o; o += (n + 255) & ~(size_t)255; return p; };
  unsigned short* xb     = (unsigned short*)take((size_t)T_TOK * HDIM * 2);
  unsigned short* WfcT   = (unsigned short*)take((size_t)NEXP * FFDIM * HDIM * 2);
  unsigned short* WprojT = (unsigned short*)take((size_t)NEXP * HDIM * FFDIM * 2);
  unsigned short* h1     = (unsigned short*)take((size_t)NPAIR * FFDIM * 2);
  unsigned short* y      = (unsigned short*)take((size_t)2 * NPAIR * HDIM * 2);
  int*   sel_e      = (int*)take(T_TOK * 2 * 4);
  float* sel_w      = (float*)take(T_TOK * 2 * 4);
  int*   pair_token = (int*)take(NPAIR * 4);
  int*   pair_pos   = (int*)take(NPAIR * 4);
  int*   counts     = (int*)take(3 * 8 * 4);
  int*   cursor     = counts + 16;

  hipMemsetAsync(counts, 0, 96, stream);   // counts + (unused) + cursor

  router_kernel<<<T_TOK / 4, 256, 0, stream>>>(x, Wg, xb, sel_e, sel_w, counts);
  fused_transpose_kernel<<<4096, 256, 0, stream>>>(Wfc, WfcT, Wproj, WprojT);
  scatter_kernel<<<T_TOK / 256, 256, 0, stream>>>(counts, sel_e, cursor, pair_token, pair_pos);

  // GEMM1: per expert, [seg x 1024] x [1024 x 4096] -> relu^2 -> h1 (bf16)
  moe_gemm_kernel<HDIM, 1, FFDIM / 256, true, true>
      <<<(FFDIM / 256) * MAXMT, 512, 0, stream>>>(xb, WfcT, counts, pair_token, h1);
  // GEMM2: per expert, [seg x 4096] x [4096 x 1024] -> split-K=2 partials y (no atomics)
  moe_gemm_kernel<FFDIM, 2, HDIM / 256, false, false>
      <<<(HDIM / 256) * 2 * MAXMT, 512, 0, stream>>>(h1, WprojT, counts, pair_token, y);
  // combine: out[t] = w0*(y0[pos0]+y1[pos0]) + w1*(y0[pos1]+y1[pos1])
  combine_kernel<<<T_TOK * (HDIM / 8) / 256, 256, 0, stream>>>(y, pair_pos, sel_w, out);
}

// Round 18
// 389.903 us; speedup vs baseline: 1.1556x; 1.0592x over previous
//
#include <hip/hip_runtime.h>

#define T_TOK 4096
#define HDIM  1024
#define NEXP  8
#define FFDIM 4096
#define NPAIR 8192   // T_TOK * topk
#define MAXMT 72     // max total 128-row M-tiles across experts: 8192/128 + 8

typedef __attribute__((ext_vector_type(8))) short short8;
typedef __attribute__((ext_vector_type(8))) unsigned short ushort8;
typedef __attribute__((ext_vector_type(4))) unsigned short ushort4_t;
typedef __attribute__((ext_vector_type(4))) float f32x4;

__device__ __forceinline__ unsigned short f2bf(float f) {
  unsigned int u = __float_as_uint(f);
  u += 0x7fffu + ((u >> 16) & 1u);   // RNE
  return (unsigned short)(u >> 16);
}
__device__ __forceinline__ float bf2f(unsigned short u) {
  return __uint_as_float((unsigned int)u << 16);
}

// global -> LDS direct copy, 16B per lane. LDS dest is wave-uniform base;
// HW writes lane l at base + l*16. Global source address is per-lane.
__device__ __forceinline__ void gload16(const void* g, const void* l) {
  __builtin_amdgcn_global_load_lds(
      (const __attribute__((address_space(1))) unsigned int*)(unsigned long long)g,
      (__attribute__((address_space(3))) unsigned int*)(unsigned int)(unsigned long long)l,
      16, 0, 0);
}

// ---------------- transpose v4 tile (512 threads, 256M x 128N) ----------------
// v3 had a 16-way LDS write conflict (lane stride 4rows x 264pitch x 2B = 2112B
// -> dword stride 528 = 16 mod 32 -> 2 banks). v4: pitch 260 + XOR-swizzle m by
// ((c>>2)&7)<<3. Write banks enumerate to 8 distinct per 8 lanes (4-way, ~free);
// read phase: per-lane distinct m0^key permutes a contiguous 512B span -> all
// banks, conflict-free. All LDS accesses stay 8/16B aligned (key uses bits 3-5).
__device__ __forceinline__ void transpose_tile_512(
    const float* __restrict__ in, unsigned short* __restrict__ out,
    int M, int N, int my, int nx, unsigned short* t /* [128][260] */) {
  int tid = threadIdx.x;
  int r0 = my * 256, c0 = nx * 128;
  int nc = tid & 31, mrb = tid >> 5;   // mrb 0..15
#pragma unroll
  for (int p = 0; p < 4; p++) {
    int mb = (p * 16 + mrb) * 4;
    int c = nc * 4;
    const float* src = in + (size_t)(r0 + mb) * N + c0 + c;
    float4 v0 = *(const float4*)(src);
    float4 v1 = *(const float4*)(src + N);
    float4 v2 = *(const float4*)(src + 2 * (size_t)N);
    float4 v3 = *(const float4*)(src + 3 * (size_t)N);
    int mi = mb ^ ((nc & 7) << 3);
    *(ushort4_t*)&t[(c + 0) * 260 + mi] = (ushort4_t){f2bf(v0.x), f2bf(v1.x), f2bf(v2.x), f2bf(v3.x)};
    *(ushort4_t*)&t[(c + 1) * 260 + mi] = (ushort4_t){f2bf(v0.y), f2bf(v1.y), f2bf(v2.y), f2bf(v3.y)};
    *(ushort4_t*)&t[(c + 2) * 260 + mi] = (ushort4_t){f2bf(v0.z), f2bf(v1.z), f2bf(v2.z), f2bf(v3.z)};
    *(ushort4_t*)&t[(c + 3) * 260 + mi] = (ushort4_t){f2bf(v0.w), f2bf(v1.w), f2bf(v2.w), f2bf(v3.w)};
  }
  __syncthreads();
  int m0 = (tid & 31) * 8, nsub = tid >> 5;
#pragma unroll
  for (int i = 0; i < 8; i++) {
    int n = i * 16 + nsub;
    int key = ((n >> 2) & 7) << 3;
    ushort8 v = *(const ushort8*)&t[n * 260 + (m0 ^ key)];
    *(ushort8*)(out + (size_t)(c0 + n) * M + r0 + m0) = v;
  }
}

// ---------------- kernel A: Wfc transpose (ids 0..1023) + router (1024..1535) ----------------
// Independent work fused into one launch so transpose blocks and router blocks
// overlap across CUs instead of serializing (~10us router hidden under the
// BW-bound transpose).
__global__ __launch_bounds__(512) void routerT_kernel(
    const float* __restrict__ x, const float* __restrict__ wg,
    unsigned short* __restrict__ xb,
    int* __restrict__ sel_e, float* __restrict__ sel_w, int* __restrict__ counts,
    const float* __restrict__ Wfc, unsigned short* __restrict__ WfcT) {
  __shared__ unsigned short tbuf[128 * 260];
  int id = blockIdx.x;
  if (id < 1024) {   // Wfc: [1024][4096] per expert -> 4 my x 32 nx
    int e = id >> 7, r = id & 127;
    transpose_tile_512(Wfc + (size_t)e * HDIM * FFDIM, WfcT + (size_t)e * HDIM * FFDIM,
                       HDIM, FFDIM, r >> 5, r & 31, tbuf);
    return;
  }
  int lane = threadIdx.x & 63;
  int t = (id - 1024) * 8 + (threadIdx.x >> 6);
  const float* xr = x + (size_t)t * HDIM;
  unsigned short* xo = xb + (size_t)t * HDIM;
  float acc[8] = {0, 0, 0, 0, 0, 0, 0, 0};
  for (int i = 0; i < HDIM / 64; i++) {
    int h = i * 64 + lane;
    float xv = xr[h];
    xo[h] = f2bf(xv);                        // fused convert_x
    float4 w0 = *(const float4*)(wg + h * 8);
    float4 w1 = *(const float4*)(wg + h * 8 + 4);
    acc[0] += xv * w0.x; acc[1] += xv * w0.y; acc[2] += xv * w0.z; acc[3] += xv * w0.w;
    acc[4] += xv * w1.x; acc[5] += xv * w1.y; acc[6] += xv * w1.z; acc[7] += xv * w1.w;
  }
#pragma unroll
  for (int off = 32; off > 0; off >>= 1) {
#pragma unroll
    for (int e = 0; e < 8; e++) acc[e] += __shfl_xor(acc[e], off, 64);
  }
  if (lane == 0) {
    int e0 = 0; float b0 = acc[0];
#pragma unroll
    for (int e = 1; e < 8; e++) if (acc[e] > b0) { b0 = acc[e]; e0 = e; }
    int e1 = -1; float b1 = -3.4e38f;
#pragma unroll
    for (int e = 0; e < 8; e++) if (e != e0 && acc[e] > b1) { b1 = acc[e]; e1 = e; }
    float q = expf(b1 - b0);                 // softmax denominator cancels in renorm
    float w0 = 1.0f / (1.0f + q);
    float w1 = q / (1.0f + q);
    sel_e[t * 2] = e0; sel_e[t * 2 + 1] = e1;
    sel_w[t * 2] = w0; sel_w[t * 2 + 1] = w1;
    atomicAdd(&counts[e0], 1);
    atomicAdd(&counts[e1], 1);
  }
}

// ---------------- scatter (offsets inline) ----------------

__global__ __launch_bounds__(256) void scatter_kernel(
    const int* __restrict__ counts, const int* __restrict__ sel_e,
    int* __restrict__ cursor, int* __restrict__ pair_token, int* __restrict__ pair_pos) {
  int t = blockIdx.x * 256 + threadIdx.x;
  int offs[NEXP];
  {
    int s = 0;
#pragma unroll
    for (int e = 0; e < NEXP; e++) { offs[e] = s; s += counts[e]; }
  }
#pragma unroll
  for (int j = 0; j < 2; j++) {
    int e = sel_e[t * 2 + j];
    int pos = offs[e] + atomicAdd(&cursor[e], 1);   // cursor zero-initialized
    pair_token[pos] = t;
    pair_pos[t * 2 + j] = pos;
  }
}

// ---------------- combine: out[t] = sum_j w_j * sum_ks y[ks][pos_j] ----------------
template <int KS>
__global__ __launch_bounds__(256) void combine_kernel(
    const unsigned short* __restrict__ y,   // [KS][NPAIR][HDIM] bf16 partials
    const int* __restrict__ pair_pos, const float* __restrict__ sel_w,
    float* __restrict__ out) {
  int i = blockIdx.x * 256 + threadIdx.x;   // over T_TOK * (HDIM/8)
  int t = i >> 7;
  int c = (i & 127) * 8;
  float r[8] = {0, 0, 0, 0, 0, 0, 0, 0};
#pragma unroll
  for (int j = 0; j < 2; j++) {
    int p = pair_pos[t * 2 + j];
    float wj = sel_w[t * 2 + j];
    float s[8] = {0, 0, 0, 0, 0, 0, 0, 0};
#pragma unroll
    for (int ks = 0; ks < KS; ks++) {
      ushort8 a = *(const ushort8*)(y + ((size_t)ks * NPAIR + p) * HDIM + c);
#pragma unroll
      for (int k = 0; k < 8; k++) s[k] += bf2f(a[k]);
    }
#pragma unroll
    for (int k = 0; k < 8; k++) r[k] += wj * s[k];
  }
  float4 v0 = {r[0], r[1], r[2], r[3]};
  float4 v1 = {r[4], r[5], r[6], r[7]};
  float* op = out + (size_t)t * HDIM + c;
  *(float4*)op = v0;
  *(float4*)(op + 4) = v1;
}

// --- expert GEMMs: r13 loop + r16 epilogue (frozen). Optional fused transpose ---
// 128x256 tile, BK=32, 3-slot ring (72KB), 8 waves (2M x 4N), wave tile 64x64,
// acc[4][4]. Per K-tile: vmcnt(3) -> s_barrier -> 8 ds_read(slot t) -> stage
// t+2 (3 gload16 -> slot t-1) -> setprio(1) 16 MFMA. Last tile vmcnt(0) (r3/r4);
// vmcnt BEFORE barrier (r7); WAR: slot t-1's reads preceded bar(t). Swizzle
// (r2/r9 pair, 0 conflicts). nt-fastest XCD work order (nb = NBG, constexpr).
// FUSET: blocks with id >= NBG transpose Wproj (runs in GEMM1's tail slack —
// ~6us of CU-time, HBM-bound where GEMM1 uses only ~19% of HBM).
template <int KD, int KSPL, int NTP, bool GATHER, bool SQRELU, bool FUSET>
__global__ __launch_bounds__(512, 4) void moe_gemm_kernel(
    const unsigned short* __restrict__ A0, const unsigned short* __restrict__ B0,
    const int* __restrict__ counts, const int* __restrict__ pair_token,
    unsigned short* __restrict__ Cout,
    const float* __restrict__ tin, unsigned short* __restrict__ tout) {
  constexpr int ND = SQRELU ? FFDIM : HDIM;
  constexpr int KLEN = KD / KSPL;
  constexpr int NTILES = KLEN / 32;
  constexpr int NBG = NTP * KSPL * MAXMT;

  __shared__ char lds[73728];          // 3 slots x (A 8KB + B 16KB); >= 66560 for transpose

  if (FUSET && blockIdx.x >= (unsigned)NBG) {
    // Wproj: [4096][1024] per expert -> 16 my x 8 nx = 128 blocks/expert
    int b = blockIdx.x - NBG;
    int e = b >> 7, r = b & 127;
    transpose_tile_512(tin + (size_t)e * FFDIM * HDIM, tout + (size_t)e * FFDIM * HDIM,
                       FFDIM, HDIM, r >> 3, r & 7, (unsigned short*)lds);
    return;
  }

  // XCD-chunked bijective swizzle over the GEMM sub-domain (NBG % 8 == 0); nt fastest
  int d = blockIdx.x;
  int w = (d & 7) * (NBG >> 3) + (d >> 3);
  int nt = w % NTP;
  int rest = w / NTP;
  int ks = rest % KSPL;
  int mt = rest / KSPL;

  // ---- expert-tile search (wave-uniform) ----
  int eSel = -1, tloc = 0, segstart = 0, segcnt = 0;
  {
    int cumt = 0, acc = 0;
#pragma unroll
    for (int ee = 0; ee < NEXP; ee++) {
      int c = counts[ee];
      int ntl = (c + 127) >> 7;
      if (eSel < 0 && mt < cumt + ntl) { eSel = ee; tloc = mt - cumt; segstart = acc; segcnt = c; }
      cumt += ntl; acc += c;
    }
  }
  if (eSel < 0) return;

  if (!SQRELU) Cout += (size_t)ks * NPAIR * HDIM;   // split-K partial buffer

  const unsigned short* B = B0 + (size_t)eSel * ND * KD + (size_t)ks * KLEN;
  const unsigned short* Abase = A0 + (size_t)ks * KLEN;

  int tid = threadIdx.x;
  int lane = tid & 63;
  int wv = tid >> 6;       // 0..7
  int wr = wv >> 2;        // 0..1  (M)
  int wc = wv & 3;         // 0..3  (N)
  int g  = lane >> 4;      // 0..3
  int lr = lane & 15;

  int srow = tid >> 2;                       // 0..127
  int schunk = (tid & 3) ^ ((tid >> 3) & 3); // pre-swizzled source chunk
  const unsigned short* aP;
  const unsigned short* bP[2];
  {
    int idx = tloc * 128 + srow;
    if (idx >= segcnt) idx = segcnt - 1;     // clamp pad rows
    int p = segstart + idx;
    size_t rowoff;
    if (GATHER) rowoff = (size_t)pair_token[p] * KD;
    else        rowoff = (size_t)p * KD;
    aP = Abase + rowoff + schunk * 8;
#pragma unroll
    for (int r = 0; r < 2; r++)
      bP[r] = B + (size_t)(nt * 256 + r * 128 + srow) * KD + schunk * 8;
  }

  const char* ldsc = lds;
  int ldsW = wv * 1024;                // wave-uniform (lane*16 added by HW)

  f32x4 acc[4][4];
#pragma unroll
  for (int i = 0; i < 4; i++)
#pragma unroll
    for (int j = 0; j < 4; j++) acc[i][j] = (f32x4){0.f, 0.f, 0.f, 0.f};

  int swz = (g ^ ((lr >> 1) & 3)) * 16;
  int abase0 = (wr * 64 + lr) * 64 + swz;            // + mi*1024
  int bbase0 = 8192 + (wc * 64 + lr) * 64 + swz;     // + nj*1024

  // prologue: stage tiles 0 and 1 into slots 0,1
#pragma unroll
  for (int t = 0; t < 2; t++) {
    int so = t * 24576;
    gload16(aP, ldsc + so + ldsW);
    gload16(bP[0], ldsc + so + 8192 + ldsW);
    gload16(bP[1], ldsc + so + 16384 + ldsW);
    aP += 32; bP[0] += 32; bP[1] += 32;
  }

  int rsOff = 0, rs2Off = 49152;
  for (int t = 0; t < NTILES; ++t) {
    if (t < NTILES - 1) {
      asm volatile("s_waitcnt vmcnt(3)" ::: "memory");
    } else {
      asm volatile("s_waitcnt vmcnt(0)" ::: "memory");
    }
    __builtin_amdgcn_s_barrier();
    __builtin_amdgcn_sched_barrier(0);

    short8 af[4], bf[4];
#pragma unroll
    for (int mi = 0; mi < 4; mi++)
      af[mi] = *(const short8*)(ldsc + rsOff + abase0 + mi * 1024);
#pragma unroll
    for (int nj = 0; nj < 4; nj++)
      bf[nj] = *(const short8*)(ldsc + rsOff + bbase0 + nj * 1024);

    if (t + 2 < NTILES) {              // stage tile t+2 into slot of tile t-1
      gload16(aP, ldsc + rs2Off + ldsW);
      gload16(bP[0], ldsc + rs2Off + 8192 + ldsW);
      gload16(bP[1], ldsc + rs2Off + 16384 + ldsW);
      aP += 32; bP[0] += 32; bP[1] += 32;
    }

    __builtin_amdgcn_s_setprio(1);
#pragma unroll
    for (int mi = 0; mi < 4; mi++)
#pragma unroll
      for (int nj = 0; nj < 4; nj++)
        acc[mi][nj] = __builtin_amdgcn_mfma_f32_16x16x32_bf16(af[mi], bf[nj], acc[mi][nj], 0, 0, 0);
    __builtin_amdgcn_s_setprio(0);

    rsOff  = (rsOff  == 49152) ? 0 : rsOff  + 24576;
    rs2Off = (rs2Off == 49152) ? 0 : rs2Off + 24576;
  }

  // ---- epilogue: LDS bounce -> coalesced ushort4 stores ----
  __syncthreads();                     // all waves done reading ring slots
  unsigned short* t2 = (unsigned short*)lds;   // [128][260]
#pragma unroll
  for (int mi = 0; mi < 4; mi++) {
#pragma unroll
    for (int q = 0; q < 4; q++) {
      int row = wr * 64 + mi * 16 + g * 4 + q;
#pragma unroll
      for (int nj = 0; nj < 4; nj++) {
        int col = wc * 64 + nj * 16 + lr;
        float v = acc[mi][nj][q];
        if (SQRELU) v = v > 0.f ? v * v : 0.f;
        t2[row * 260 + col] = f2bf(v);
      }
    }
  }
  __syncthreads();
  {
    int row = tid >> 2;                // 0..127
    int idx = tloc * 128 + row;
    if (idx < segcnt) {
      size_t base = (size_t)(segstart + idx) * ND + nt * 256;
      const unsigned short* src = t2 + row * 260;
#pragma unroll
      for (int i = 0; i < 16; i++) {
        int c = ((tid & 3) + i * 4) * 4;
        *(ushort4_t*)(Cout + base + c) = *(const ushort4_t*)(src + c);
      }
    }
  }
}

// ---------------- launch ----------------

extern "C" void kernel_launch(void* const* d_in, const int* in_sizes, int n_in,
                              void* d_out, int out_size, void* d_ws, size_t ws_size,
                              hipStream_t stream) {
  (void)in_sizes; (void)n_in; (void)out_size;
  const float* x     = (const float*)d_in[0];
  const float* Wg    = (const float*)d_in[1];
  const float* Wfc   = (const float*)d_in[2];
  const float* Wproj = (const float*)d_in[3];
  float* out = (float*)d_out;

  char* w = (char*)d_ws;
  size_t o = 0;
  auto take = [&](size_t n) { char* p = w + o; o += (n + 255) & ~(size_t)255; return p; };
  unsigned short* xb     = (unsigned short*)take((size_t)T_TOK * HDIM * 2);
  unsigned short* WfcT   = (unsigned short*)take((size_t)NEXP * FFDIM * HDIM * 2);
  unsigned short* WprojT = (unsigned short*)take((size_t)NEXP * HDIM * FFDIM * 2);
  unsigned short* h1     = (unsigned short*)take((size_t)NPAIR * FFDIM * 2);
  // y: prefer 4 split-K partials (better GEMM2 makespan) if workspace allows
  size_t fixed = o + (size_t)T_TOK * 2 * 4 * 3 + NPAIR * 4 * 2 + 512;
  bool ks4 = ws_size >= fixed + (size_t)4 * NPAIR * HDIM * 2;
  unsigned short* y = (unsigned short*)take((size_t)(ks4 ? 4 : 2) * NPAIR * HDIM * 2);
  int*   sel_e      = (int*)take(T_TOK * 2 * 4);
  float* sel_w      = (float*)take(T_TOK * 2 * 4);
  int*   pair_token = (int*)take(NPAIR * 4);
  int*   pair_pos   = (int*)take(NPAIR * 4);
  int*   counts     = (int*)take(3 * 8 * 4);
  int*   cursor     = counts + 16;

  hipMemsetAsync(counts, 0, 96, stream);

  // A: Wfc transpose (1024 blocks) + router (512 blocks), overlapped
  routerT_kernel<<<1536, 512, 0, stream>>>(x, Wg, xb, sel_e, sel_w, counts, Wfc, WfcT);
  scatter_kernel<<<T_TOK / 256, 256, 0, stream>>>(counts, sel_e, cursor, pair_token, pair_pos);

  // GEMM1 (1152 blocks) + Wproj transpose (1024 blocks) fused
  moe_gemm_kernel<HDIM, 1, FFDIM / 256, true, true, true>
      <<<(FFDIM / 256) * MAXMT + 1024, 512, 0, stream>>>(
          xb, WfcT, counts, pair_token, h1, Wproj, WprojT);
  // GEMM2: split-K partials y (no atomics); KSPL=4 if workspace allows (tail balance)
  if (ks4) {
    moe_gemm_kernel<FFDIM, 4, HDIM / 256, false, false, false>
        <<<(HDIM / 256) * 4 * MAXMT, 512, 0, stream>>>(
            h1, WprojT, counts, pair_token, y, nullptr, nullptr);
    combine_kernel<4><<<T_TOK * (HDIM / 8) / 256, 256, 0, stream>>>(y, pair_pos, sel_w, out);
  } else {
    moe_gemm_kernel<FFDIM, 2, HDIM / 256, false, false, false>
        <<<(HDIM / 256) * 2 * MAXMT, 512, 0, stream>>>(
            h1, WprojT, counts, pair_token, y, nullptr, nullptr);
    combine_kernel<2><<<T_TOK * (HDIM / 8) / 256, 256, 0, stream>>>(y, pair_pos, sel_w, out);
  }
}

// Round 19
// 292.480 us; speedup vs baseline: 1.5405x; 1.3331x over previous
//
#include <hip/hip_runtime.h>

#define T_TOK 4096
#define HDIM  1024
#define NEXP  8
#define FFDIM 4096
#define NPAIR 8192   // T_TOK * topk
#define MAXMT 72     // max total 128-row M-tiles across experts: 8192/128 + 8

typedef __attribute__((ext_vector_type(8))) short short8;
typedef __attribute__((ext_vector_type(8))) unsigned short ushort8;
typedef __attribute__((ext_vector_type(4))) unsigned short ushort4_t;
typedef __attribute__((ext_vector_type(4))) float f32x4;

__device__ __forceinline__ unsigned short f2bf(float f) {
  unsigned int u = __float_as_uint(f);
  u += 0x7fffu + ((u >> 16) & 1u);   // RNE
  return (unsigned short)(u >> 16);
}
__device__ __forceinline__ float bf2f(unsigned short u) {
  return __uint_as_float((unsigned int)u << 16);
}

// global -> LDS direct copy, 16B per lane. LDS dest is wave-uniform base;
// HW writes lane l at base + l*16. Global source address is per-lane.
__device__ __forceinline__ void gload16(const void* g, const void* l) {
  __builtin_amdgcn_global_load_lds(
      (const __attribute__((address_space(1))) unsigned int*)(unsigned long long)g,
      (__attribute__((address_space(3))) unsigned int*)(unsigned int)(unsigned long long)l,
      16, 0, 0);
}

// ---------------- transpose tile v2 (r14-verified), 256 threads, 256M x 64N ----------------
__device__ __forceinline__ void transpose_tile_256(
    const float* __restrict__ in, unsigned short* __restrict__ out,
    int M, int N, int my, int nx, unsigned short* t /* [64][264] */) {
  int tid = threadIdx.x;
  int r0 = my * 256, c0 = nx * 64;
  int colb = (tid & 15) * 4;
  int rowi = tid >> 4;
  int sw = (tid & 7) << 3;
#pragma unroll
  for (int i = 0; i < 16; i++) {
    int row = i * 16 + rowi;
    float4 v = *(const float4*)(in + (size_t)(r0 + row) * N + c0 + colb);
    int rs = row ^ sw;
    t[(colb + 0) * 264 + rs] = f2bf(v.x);
    t[(colb + 1) * 264 + rs] = f2bf(v.y);
    t[(colb + 2) * 264 + rs] = f2bf(v.z);
    t[(colb + 3) * 264 + rs] = f2bf(v.w);
  }
  __syncthreads();
  int m0 = (tid & 31) * 8;
  int nsub = tid >> 5;
#pragma unroll
  for (int i = 0; i < 8; i++) {
    int n = i * 8 + nsub;
    int sn = ((n >> 2) & 7) << 3;
    ushort8 v = *(const ushort8*)&t[n * 264 + (m0 ^ sn)];
    *(ushort8*)(out + (size_t)(c0 + n) * M + r0 + m0) = v;
  }
}

// ---------------- transpose tile v4 (512 threads, 256M x 128N) for GEMM1 fusion ----------------
__device__ __forceinline__ void transpose_tile_512(
    const float* __restrict__ in, unsigned short* __restrict__ out,
    int M, int N, int my, int nx, unsigned short* t /* [128][260] */) {
  int tid = threadIdx.x;
  int r0 = my * 256, c0 = nx * 128;
  int nc = tid & 31, mrb = tid >> 5;
#pragma unroll
  for (int p = 0; p < 4; p++) {
    int mb = (p * 16 + mrb) * 4;
    int c = nc * 4;
    const float* src = in + (size_t)(r0 + mb) * N + c0 + c;
    float4 v0 = *(const float4*)(src);
    float4 v1 = *(const float4*)(src + N);
    float4 v2 = *(const float4*)(src + 2 * (size_t)N);
    float4 v3 = *(const float4*)(src + 3 * (size_t)N);
    int mi = mb ^ ((nc & 7) << 3);
    *(ushort4_t*)&t[(c + 0) * 260 + mi] = (ushort4_t){f2bf(v0.x), f2bf(v1.x), f2bf(v2.x), f2bf(v3.x)};
    *(ushort4_t*)&t[(c + 1) * 260 + mi] = (ushort4_t){f2bf(v0.y), f2bf(v1.y), f2bf(v2.y), f2bf(v3.y)};
    *(ushort4_t*)&t[(c + 2) * 260 + mi] = (ushort4_t){f2bf(v0.z), f2bf(v1.z), f2bf(v2.z), f2bf(v3.z)};
    *(ushort4_t*)&t[(c + 3) * 260 + mi] = (ushort4_t){f2bf(v0.w), f2bf(v1.w), f2bf(v2.w), f2bf(v3.w)};
  }
  __syncthreads();
  int m0 = (tid & 31) * 8, nsub = tid >> 5;
#pragma unroll
  for (int i = 0; i < 8; i++) {
    int n = i * 16 + nsub;
    int key = ((n >> 2) & 7) << 3;
    ushort8 v = *(const ushort8*)&t[n * 260 + (m0 ^ key)];
    *(ushort8*)(out + (size_t)(c0 + n) * M + r0 + m0) = v;
  }
}

// ---- kernel A: router v2 (ids 0..1023, ATOMIC-FREE, vectorized) + WfcT tiles ----
__global__ __launch_bounds__(256) void routerA_kernel(
    const float* __restrict__ x, const float* __restrict__ wg,
    unsigned short* __restrict__ xb,
    int* __restrict__ sel_e, float* __restrict__ sel_w,
    const float* __restrict__ Wfc, unsigned short* __restrict__ WfcT) {
  __shared__ unsigned short tbuf[64 * 264];
  int id = blockIdx.x;
  if (id >= 1024) {   // Wfc: [1024][4096] per expert -> 4 my x 64 nx = 256 tiles
    int b = id - 1024;
    int e = b >> 8, r = b & 255;
    transpose_tile_256(Wfc + (size_t)e * HDIM * FFDIM, WfcT + (size_t)e * HDIM * FFDIM,
                       HDIM, FFDIM, r >> 6, r & 63, tbuf);
    return;
  }
  int lane = threadIdx.x & 63;
  int t = id * 4 + (threadIdx.x >> 6);
  const float* xr = x + (size_t)t * HDIM;
  unsigned short* xo = xb + (size_t)t * HDIM;
  float acc[8] = {0, 0, 0, 0, 0, 0, 0, 0};
#pragma unroll
  for (int i = 0; i < 4; i++) {
    int h0 = i * 256 + lane * 4;
    float4 xv = *(const float4*)(xr + h0);
    *(ushort4_t*)(xo + h0) = (ushort4_t){f2bf(xv.x), f2bf(xv.y), f2bf(xv.z), f2bf(xv.w)};
    float xs[4] = {xv.x, xv.y, xv.z, xv.w};
#pragma unroll
    for (int k = 0; k < 4; k++) {
      const float* wr_ = wg + (size_t)(h0 + k) * 8;
      float4 w0 = *(const float4*)(wr_);
      float4 w1 = *(const float4*)(wr_ + 4);
      acc[0] += xs[k] * w0.x; acc[1] += xs[k] * w0.y; acc[2] += xs[k] * w0.z; acc[3] += xs[k] * w0.w;
      acc[4] += xs[k] * w1.x; acc[5] += xs[k] * w1.y; acc[6] += xs[k] * w1.z; acc[7] += xs[k] * w1.w;
    }
  }
#pragma unroll
  for (int off = 32; off > 0; off >>= 1) {
#pragma unroll
    for (int e = 0; e < 8; e++) acc[e] += __shfl_xor(acc[e], off, 64);
  }
  if (lane == 0) {
    int e0 = 0; float b0 = acc[0];
#pragma unroll
    for (int e = 1; e < 8; e++) if (acc[e] > b0) { b0 = acc[e]; e0 = e; }
    int e1 = -1; float b1 = -3.4e38f;
#pragma unroll
    for (int e = 0; e < 8; e++) if (e != e0 && acc[e] > b1) { b1 = acc[e]; e1 = e; }
    float q = expf(b1 - b0);                 // softmax denominator cancels in renorm
    float w0 = 1.0f / (1.0f + q);
    float w1 = q / (1.0f + q);
    sel_e[t * 2] = e0; sel_e[t * 2 + 1] = e1;
    sel_w[t * 2] = w0; sel_w[t * 2 + 1] = w1;
  }
}

// ---- count+scatter: ONE block, LDS cursors (replaces global-atomic scatter) ----
// Wave-local histograms -> serial prefix -> per-wave LDS cursor scatter.
// Intra-expert permutation is downstream-invariant (GEMM rows independent;
// combine reads via pair_pos), so d_out is deterministic.
__global__ __launch_bounds__(1024) void count_scatter_kernel(
    const int* __restrict__ sel_e, int* __restrict__ counts,
    int* __restrict__ pair_token, int* __restrict__ pair_pos) {
  __shared__ int wtot[16][NEXP];
  __shared__ int wcur[16][NEXP];
  int tid = threadIdx.x;
  int wv = tid >> 6;
  int lane = tid & 63;
  int4 a = *(const int4*)(sel_e + tid * 8);
  int4 b = *(const int4*)(sel_e + tid * 8 + 4);
  int es[8] = {a.x, a.y, a.z, a.w, b.x, b.y, b.z, b.w};
  int c[NEXP] = {0, 0, 0, 0, 0, 0, 0, 0};
#pragma unroll
  for (int j = 0; j < 8; j++) c[es[j]]++;
#pragma unroll
  for (int off = 32; off > 0; off >>= 1)
#pragma unroll
    for (int e = 0; e < NEXP; e++) c[e] += __shfl_xor(c[e], off, 64);
  if (lane == 0)
#pragma unroll
    for (int e = 0; e < NEXP; e++) wtot[wv][e] = c[e];
  __syncthreads();
  if (tid == 0) {
    int tot[NEXP];
#pragma unroll
    for (int e = 0; e < NEXP; e++) {
      int s = 0;
      for (int w2 = 0; w2 < 16; w2++) s += wtot[w2][e];
      tot[e] = s;
    }
    int s = 0;
    for (int e = 0; e < NEXP; e++) {
      counts[e] = tot[e];
      int base = s;
      for (int w2 = 0; w2 < 16; w2++) { wcur[w2][e] = base; base += wtot[w2][e]; }
      s += tot[e];
    }
  }
  __syncthreads();
#pragma unroll
  for (int j = 0; j < 8; j++) {
    int e = es[j];
    int pos = atomicAdd(&wcur[wv][e], 1);      // LDS atomic, per-wave cursor
    int entry = tid * 8 + j;
    pair_token[pos] = entry >> 1;
    pair_pos[entry] = pos;
  }
}

// ---------------- combine: out[t] = sum_j w_j * sum_ks y[ks][pos_j] ----------------
template <int KS>
__global__ __launch_bounds__(256) void combine_kernel(
    const unsigned short* __restrict__ y,   // [KS][NPAIR][HDIM] bf16 partials
    const int* __restrict__ pair_pos, const float* __restrict__ sel_w,
    float* __restrict__ out) {
  int i = blockIdx.x * 256 + threadIdx.x;   // over T_TOK * (HDIM/8)
  int t = i >> 7;
  int c = (i & 127) * 8;
  float r[8] = {0, 0, 0, 0, 0, 0, 0, 0};
#pragma unroll
  for (int j = 0; j < 2; j++) {
    int p = pair_pos[t * 2 + j];
    float wj = sel_w[t * 2 + j];
    float s[8] = {0, 0, 0, 0, 0, 0, 0, 0};
#pragma unroll
    for (int ks = 0; ks < KS; ks++) {
      ushort8 a = *(const ushort8*)(y + ((size_t)ks * NPAIR + p) * HDIM + c);
#pragma unroll
      for (int k = 0; k < 8; k++) s[k] += bf2f(a[k]);
    }
#pragma unroll
    for (int k = 0; k < 8; k++) r[k] += wj * s[k];
  }
  float4 v0 = {r[0], r[1], r[2], r[3]};
  float4 v1 = {r[4], r[5], r[6], r[7]};
  float* op = out + (size_t)t * HDIM + c;
  *(float4*)op = v0;
  *(float4*)(op + 4) = v1;
}

// --- expert GEMMs: r13 loop + r16 epilogue (frozen). FUSET: WprojT in tail ---
template <int KD, int KSPL, int NTP, bool GATHER, bool SQRELU, bool FUSET>
__global__ __launch_bounds__(512, 4) void moe_gemm_kernel(
    const unsigned short* __restrict__ A0, const unsigned short* __restrict__ B0,
    const int* __restrict__ counts, const int* __restrict__ pair_token,
    unsigned short* __restrict__ Cout,
    const float* __restrict__ tin, unsigned short* __restrict__ tout) {
  constexpr int ND = SQRELU ? FFDIM : HDIM;
  constexpr int KLEN = KD / KSPL;
  constexpr int NTILES = KLEN / 32;
  constexpr int NBG = NTP * KSPL * MAXMT;

  __shared__ char lds[73728];          // 3 slots x (A 8KB + B 16KB); >= 66560 for transpose

  if (FUSET && blockIdx.x >= (unsigned)NBG) {
    // Wproj: [4096][1024] per expert -> 16 my x 8 nx = 128 blocks/expert
    int b = blockIdx.x - NBG;
    int e = b >> 7, r = b & 127;
    transpose_tile_512(tin + (size_t)e * FFDIM * HDIM, tout + (size_t)e * FFDIM * HDIM,
                       FFDIM, HDIM, r >> 3, r & 7, (unsigned short*)lds);
    return;
  }

  // XCD-chunked bijective swizzle over the GEMM sub-domain (NBG % 8 == 0); nt fastest
  int d = blockIdx.x;
  int w = (d & 7) * (NBG >> 3) + (d >> 3);
  int nt = w % NTP;
  int rest = w / NTP;
  int ks = rest % KSPL;
  int mt = rest / KSPL;

  // ---- expert-tile search (wave-uniform) ----
  int eSel = -1, tloc = 0, segstart = 0, segcnt = 0;
  {
    int cumt = 0, acc = 0;
#pragma unroll
    for (int ee = 0; ee < NEXP; ee++) {
      int c = counts[ee];
      int ntl = (c + 127) >> 7;
      if (eSel < 0 && mt < cumt + ntl) { eSel = ee; tloc = mt - cumt; segstart = acc; segcnt = c; }
      cumt += ntl; acc += c;
    }
  }
  if (eSel < 0) return;

  if (!SQRELU) Cout += (size_t)ks * NPAIR * HDIM;   // split-K partial buffer

  const unsigned short* B = B0 + (size_t)eSel * ND * KD + (size_t)ks * KLEN;
  const unsigned short* Abase = A0 + (size_t)ks * KLEN;

  int tid = threadIdx.x;
  int lane = tid & 63;
  int wv = tid >> 6;       // 0..7
  int wr = wv >> 2;        // 0..1  (M)
  int wc = wv & 3;         // 0..3  (N)
  int g  = lane >> 4;      // 0..3
  int lr = lane & 15;

  int srow = tid >> 2;                       // 0..127
  int schunk = (tid & 3) ^ ((tid >> 3) & 3); // pre-swizzled source chunk
  const unsigned short* aP;
  const unsigned short* bP[2];
  {
    int idx = tloc * 128 + srow;
    if (idx >= segcnt) idx = segcnt - 1;     // clamp pad rows
    int p = segstart + idx;
    size_t rowoff;
    if (GATHER) rowoff = (size_t)pair_token[p] * KD;
    else        rowoff = (size_t)p * KD;
    aP = Abase + rowoff + schunk * 8;
#pragma unroll
    for (int r = 0; r < 2; r++)
      bP[r] = B + (size_t)(nt * 256 + r * 128 + srow) * KD + schunk * 8;
  }

  const char* ldsc = lds;
  int ldsW = wv * 1024;                // wave-uniform (lane*16 added by HW)

  f32x4 acc[4][4];
#pragma unroll
  for (int i = 0; i < 4; i++)
#pragma unroll
    for (int j = 0; j < 4; j++) acc[i][j] = (f32x4){0.f, 0.f, 0.f, 0.f};

  int swz = (g ^ ((lr >> 1) & 3)) * 16;
  int abase0 = (wr * 64 + lr) * 64 + swz;            // + mi*1024
  int bbase0 = 8192 + (wc * 64 + lr) * 64 + swz;     // + nj*1024

  // prologue: stage tiles 0 and 1 into slots 0,1
#pragma unroll
  for (int t = 0; t < 2; t++) {
    int so = t * 24576;
    gload16(aP, ldsc + so + ldsW);
    gload16(bP[0], ldsc + so + 8192 + ldsW);
    gload16(bP[1], ldsc + so + 16384 + ldsW);
    aP += 32; bP[0] += 32; bP[1] += 32;
  }

  int rsOff = 0, rs2Off = 49152;
  for (int t = 0; t < NTILES; ++t) {
    if (t < NTILES - 1) {
      asm volatile("s_waitcnt vmcnt(3)" ::: "memory");
    } else {
      asm volatile("s_waitcnt vmcnt(0)" ::: "memory");
    }
    __builtin_amdgcn_s_barrier();
    __builtin_amdgcn_sched_barrier(0);

    short8 af[4], bf[4];
#pragma unroll
    for (int mi = 0; mi < 4; mi++)
      af[mi] = *(const short8*)(ldsc + rsOff + abase0 + mi * 1024);
#pragma unroll
    for (int nj = 0; nj < 4; nj++)
      bf[nj] = *(const short8*)(ldsc + rsOff + bbase0 + nj * 1024);

    if (t + 2 < NTILES) {              // stage tile t+2 into slot of tile t-1
      gload16(aP, ldsc + rs2Off + ldsW);
      gload16(bP[0], ldsc + rs2Off + 8192 + ldsW);
      gload16(bP[1], ldsc + rs2Off + 16384 + ldsW);
      aP += 32; bP[0] += 32; bP[1] += 32;
    }

    __builtin_amdgcn_s_setprio(1);
#pragma unroll
    for (int mi = 0; mi < 4; mi++)
#pragma unroll
      for (int nj = 0; nj < 4; nj++)
        acc[mi][nj] = __builtin_amdgcn_mfma_f32_16x16x32_bf16(af[mi], bf[nj], acc[mi][nj], 0, 0, 0);
    __builtin_amdgcn_s_setprio(0);

    rsOff  = (rsOff  == 49152) ? 0 : rsOff  + 24576;
    rs2Off = (rs2Off == 49152) ? 0 : rs2Off + 24576;
  }

  // ---- epilogue: LDS bounce -> coalesced ushort4 stores ----
  __syncthreads();                     // all waves done reading ring slots
  unsigned short* t2 = (unsigned short*)lds;   // [128][260]
#pragma unroll
  for (int mi = 0; mi < 4; mi++) {
#pragma unroll
    for (int q = 0; q < 4; q++) {
      int row = wr * 64 + mi * 16 + g * 4 + q;
#pragma unroll
      for (int nj = 0; nj < 4; nj++) {
        int col = wc * 64 + nj * 16 + lr;
        float v = acc[mi][nj][q];
        if (SQRELU) v = v > 0.f ? v * v : 0.f;
        t2[row * 260 + col] = f2bf(v);
      }
    }
  }
  __syncthreads();
  {
    int row = tid >> 2;                // 0..127
    int idx = tloc * 128 + row;
    if (idx < segcnt) {
      size_t base = (size_t)(segstart + idx) * ND + nt * 256;
      const unsigned short* src = t2 + row * 260;
#pragma unroll
      for (int i = 0; i < 16; i++) {
        int c = ((tid & 3) + i * 4) * 4;
        *(ushort4_t*)(Cout + base + c) = *(const ushort4_t*)(src + c);
      }
    }
  }
}

// ---------------- launch ----------------

extern "C" void kernel_launch(void* const* d_in, const int* in_sizes, int n_in,
                              void* d_out, int out_size, void* d_ws, size_t ws_size,
                              hipStream_t stream) {
  (void)in_sizes; (void)n_in; (void)out_size;
  const float* x     = (const float*)d_in[0];
  const float* Wg    = (const float*)d_in[1];
  const float* Wfc   = (const float*)d_in[2];
  const float* Wproj = (const float*)d_in[3];
  float* out = (float*)d_out;

  char* w = (char*)d_ws;
  size_t o = 0;
  auto take = [&](size_t n) { char* p = w + o; o += (n + 255) & ~(size_t)255; return p; };
  unsigned short* xb     = (unsigned short*)take((size_t)T_TOK * HDIM * 2);
  unsigned short* WfcT   = (unsigned short*)take((size_t)NEXP * FFDIM * HDIM * 2);
  unsigned short* WprojT = (unsigned short*)take((size_t)NEXP * HDIM * FFDIM * 2);
  unsigned short* h1     = (unsigned short*)take((size_t)NPAIR * FFDIM * 2);
  // y: prefer 4 split-K partials (better GEMM2 makespan) if workspace allows
  size_t fixed = o + (size_t)T_TOK * 2 * 4 * 3 + NPAIR * 4 * 2 + 512;
  bool ks4 = ws_size >= fixed + (size_t)4 * NPAIR * HDIM * 2;
  unsigned short* y = (unsigned short*)take((size_t)(ks4 ? 4 : 2) * NPAIR * HDIM * 2);
  int*   sel_e      = (int*)take(T_TOK * 2 * 4);
  float* sel_w      = (float*)take(T_TOK * 2 * 4);
  int*   pair_token = (int*)take(NPAIR * 4);
  int*   pair_pos   = (int*)take(NPAIR * 4);
  int*   counts     = (int*)take(8 * 4);

  // A: router (1024 blocks, atomic-free) + Wfc transpose (2048 blocks), overlapped
  routerA_kernel<<<3072, 256, 0, stream>>>(x, Wg, xb, sel_e, sel_w, Wfc, WfcT);
  // B: single-block count + scatter via LDS cursors (no global atomics)
  count_scatter_kernel<<<1, 1024, 0, stream>>>(sel_e, counts, pair_token, pair_pos);

  // GEMM1 (1152 blocks) + Wproj transpose (1024 blocks) fused
  moe_gemm_kernel<HDIM, 1, FFDIM / 256, true, true, true>
      <<<(FFDIM / 256) * MAXMT + 1024, 512, 0, stream>>>(
          xb, WfcT, counts, pair_token, h1, Wproj, WprojT);
  // GEMM2: split-K partials y (no atomics); KSPL=4 if workspace allows (tail balance)
  if (ks4) {
    moe_gemm_kernel<FFDIM, 4, HDIM / 256, false, false, false>
        <<<(HDIM / 256) * 4 * MAXMT, 512, 0, stream>>>(
            h1, WprojT, counts, pair_token, y, nullptr, nullptr);
    combine_kernel<4><<<T_TOK * (HDIM / 8) / 256, 256, 0, stream>>>(y, pair_pos, sel_w, out);
  } else {
    moe_gemm_kernel<FFDIM, 2, HDIM / 256, false, false, false>
        <<<(HDIM / 256) * 2 * MAXMT, 512, 0, stream>>>(
            h1, WprojT, counts, pair_token, y, nullptr, nullptr);
    combine_kernel<2><<<T_TOK * (HDIM / 8) / 256, 256, 0, stream>>>(y, pair_pos, sel_w, out);
  }
}

// Round 20
// 287.596 us; speedup vs baseline: 1.5667x; 1.0170x over previous
//
#include <hip/hip_runtime.h>

#define T_TOK 4096
#define HDIM  1024
#define NEXP  8
#define FFDIM 4096
#define NPAIR 8192   // T_TOK * topk
#define MAXMT 72     // max total 128-row M-tiles across experts: 8192/128 + 8

typedef __attribute__((ext_vector_type(8))) short short8;
typedef __attribute__((ext_vector_type(8))) unsigned short ushort8;
typedef __attribute__((ext_vector_type(4))) unsigned short ushort4_t;
typedef __attribute__((ext_vector_type(4))) float f32x4;

__device__ __forceinline__ unsigned short f2bf(float f) {
  unsigned int u = __float_as_uint(f);
  u += 0x7fffu + ((u >> 16) & 1u);   // RNE
  return (unsigned short)(u >> 16);
}
__device__ __forceinline__ float bf2f(unsigned short u) {
  return __uint_as_float((unsigned int)u << 16);
}

// global -> LDS direct copy, 16B per lane. LDS dest is wave-uniform base;
// HW writes lane l at base + l*16. Global source address is per-lane.
__device__ __forceinline__ void gload16(const void* g, const void* l) {
  __builtin_amdgcn_global_load_lds(
      (const __attribute__((address_space(1))) unsigned int*)(unsigned long long)g,
      (__attribute__((address_space(3))) unsigned int*)(unsigned int)(unsigned long long)l,
      16, 0, 0);
}

// ---------------- transpose tile v2 (r14-verified pattern), 256 lanes, 256M x 64N ----------------
// tid parameterized so two tiles can run side-by-side in a 512-thread block.
// Writes: scalar b16 with row XOR sw (measured 0-conflict in r14/r19); reads:
// ushort8, 16B-aligned contiguous.
__device__ __forceinline__ void transpose_tile_256(
    const float* __restrict__ in, unsigned short* __restrict__ out,
    int M, int N, int my, int nx, unsigned short* t /* [64][264] */, int tid) {
  int r0 = my * 256, c0 = nx * 64;
  int colb = (tid & 15) * 4;
  int rowi = tid >> 4;
  int sw = (tid & 7) << 3;
#pragma unroll
  for (int i = 0; i < 16; i++) {
    int row = i * 16 + rowi;
    float4 v = *(const float4*)(in + (size_t)(r0 + row) * N + c0 + colb);
    int rs = row ^ sw;
    t[(colb + 0) * 264 + rs] = f2bf(v.x);
    t[(colb + 1) * 264 + rs] = f2bf(v.y);
    t[(colb + 2) * 264 + rs] = f2bf(v.z);
    t[(colb + 3) * 264 + rs] = f2bf(v.w);
  }
  __syncthreads();
  int m0 = (tid & 31) * 8;
  int nsub = tid >> 5;
#pragma unroll
  for (int i = 0; i < 8; i++) {
    int n = i * 8 + nsub;
    int sn = ((n >> 2) & 7) << 3;
    ushort8 v = *(const ushort8*)&t[n * 264 + (m0 ^ sn)];
    *(ushort8*)(out + (size_t)(c0 + n) * M + r0 + m0) = v;
  }
}

// ---- kernel A: router (ids 0..1023, ATOMIC-FREE, vectorized) + WfcT v2 tiles ----
__global__ __launch_bounds__(256) void routerA_kernel(
    const float* __restrict__ x, const float* __restrict__ wg,
    unsigned short* __restrict__ xb,
    int* __restrict__ sel_e, float* __restrict__ sel_w,
    const float* __restrict__ Wfc, unsigned short* __restrict__ WfcT) {
  __shared__ unsigned short tbuf[64 * 264];
  int id = blockIdx.x;
  if (id >= 1024) {   // Wfc: [1024][4096] per expert -> 4 my x 64 nx = 256 tiles
    int b = id - 1024;
    int e = b >> 8, r = b & 255;
    transpose_tile_256(Wfc + (size_t)e * HDIM * FFDIM, WfcT + (size_t)e * HDIM * FFDIM,
                       HDIM, FFDIM, r >> 6, r & 63, tbuf, threadIdx.x);
    return;
  }
  int lane = threadIdx.x & 63;
  int t = id * 4 + (threadIdx.x >> 6);
  const float* xr = x + (size_t)t * HDIM;
  unsigned short* xo = xb + (size_t)t * HDIM;
  float acc[8] = {0, 0, 0, 0, 0, 0, 0, 0};
#pragma unroll
  for (int i = 0; i < 4; i++) {
    int h0 = i * 256 + lane * 4;
    float4 xv = *(const float4*)(xr + h0);
    *(ushort4_t*)(xo + h0) = (ushort4_t){f2bf(xv.x), f2bf(xv.y), f2bf(xv.z), f2bf(xv.w)};
    float xs[4] = {xv.x, xv.y, xv.z, xv.w};
#pragma unroll
    for (int k = 0; k < 4; k++) {
      const float* wr_ = wg + (size_t)(h0 + k) * 8;
      float4 w0 = *(const float4*)(wr_);
      float4 w1 = *(const float4*)(wr_ + 4);
      acc[0] += xs[k] * w0.x; acc[1] += xs[k] * w0.y; acc[2] += xs[k] * w0.z; acc[3] += xs[k] * w0.w;
      acc[4] += xs[k] * w1.x; acc[5] += xs[k] * w1.y; acc[6] += xs[k] * w1.z; acc[7] += xs[k] * w1.w;
    }
  }
#pragma unroll
  for (int off = 32; off > 0; off >>= 1) {
#pragma unroll
    for (int e = 0; e < 8; e++) acc[e] += __shfl_xor(acc[e], off, 64);
  }
  if (lane == 0) {
    int e0 = 0; float b0 = acc[0];
#pragma unroll
    for (int e = 1; e < 8; e++) if (acc[e] > b0) { b0 = acc[e]; e0 = e; }
    int e1 = -1; float b1 = -3.4e38f;
#pragma unroll
    for (int e = 0; e < 8; e++) if (e != e0 && acc[e] > b1) { b1 = acc[e]; e1 = e; }
    float q = expf(b1 - b0);                 // softmax denominator cancels in renorm
    float w0 = 1.0f / (1.0f + q);
    float w1 = q / (1.0f + q);
    sel_e[t * 2] = e0; sel_e[t * 2 + 1] = e1;
    sel_w[t * 2] = w0; sel_w[t * 2 + 1] = w1;
  }
}

// ---- count+scatter: ONE block, LDS cursors (no global atomics) ----
__global__ __launch_bounds__(1024) void count_scatter_kernel(
    const int* __restrict__ sel_e, int* __restrict__ counts,
    int* __restrict__ pair_token, int* __restrict__ pair_pos) {
  __shared__ int wtot[16][NEXP];
  __shared__ int wcur[16][NEXP];
  int tid = threadIdx.x;
  int wv = tid >> 6;
  int lane = tid & 63;
  int4 a = *(const int4*)(sel_e + tid * 8);
  int4 b = *(const int4*)(sel_e + tid * 8 + 4);
  int es[8] = {a.x, a.y, a.z, a.w, b.x, b.y, b.z, b.w};
  int c[NEXP] = {0, 0, 0, 0, 0, 0, 0, 0};
#pragma unroll
  for (int j = 0; j < 8; j++) c[es[j]]++;
#pragma unroll
  for (int off = 32; off > 0; off >>= 1)
#pragma unroll
    for (int e = 0; e < NEXP; e++) c[e] += __shfl_xor(c[e], off, 64);
  if (lane == 0)
#pragma unroll
    for (int e = 0; e < NEXP; e++) wtot[wv][e] = c[e];
  __syncthreads();
  if (tid == 0) {
    int tot[NEXP];
#pragma unroll
    for (int e = 0; e < NEXP; e++) {
      int s = 0;
      for (int w2 = 0; w2 < 16; w2++) s += wtot[w2][e];
      tot[e] = s;
    }
    int s = 0;
    for (int e = 0; e < NEXP; e++) {
      counts[e] = tot[e];
      int base = s;
      for (int w2 = 0; w2 < 16; w2++) { wcur[w2][e] = base; base += wtot[w2][e]; }
      s += tot[e];
    }
  }
  __syncthreads();
#pragma unroll
  for (int j = 0; j < 8; j++) {
    int e = es[j];
    int pos = atomicAdd(&wcur[wv][e], 1);      // LDS atomic, per-wave cursor
    int entry = tid * 8 + j;
    pair_token[pos] = entry >> 1;
    pair_pos[entry] = pos;
  }
}

// ---------------- combine: out[t] = sum_j w_j * (y0[pos_j] + y1[pos_j]) ----------------
__global__ __launch_bounds__(256) void combine_kernel(
    const unsigned short* __restrict__ y,   // [2][NPAIR][HDIM] bf16 partials
    const int* __restrict__ pair_pos, const float* __restrict__ sel_w,
    float* __restrict__ out) {
  int i = blockIdx.x * 256 + threadIdx.x;   // over T_TOK * (HDIM/8)
  int t = i >> 7;
  int c = (i & 127) * 8;
  int p0 = pair_pos[t * 2], p1 = pair_pos[t * 2 + 1];
  float w0 = sel_w[t * 2], w1 = sel_w[t * 2 + 1];
  const unsigned short* y1p = y + (size_t)NPAIR * HDIM;
  ushort8 a0 = *(const ushort8*)(y + (size_t)p0 * HDIM + c);
  ushort8 b0 = *(const ushort8*)(y1p + (size_t)p0 * HDIM + c);
  ushort8 a1 = *(const ushort8*)(y + (size_t)p1 * HDIM + c);
  ushort8 b1 = *(const ushort8*)(y1p + (size_t)p1 * HDIM + c);
  float r[8];
#pragma unroll
  for (int j = 0; j < 8; j++)
    r[j] = w0 * (bf2f(a0[j]) + bf2f(b0[j])) + w1 * (bf2f(a1[j]) + bf2f(b1[j]));
  float4 v0 = {r[0], r[1], r[2], r[3]};
  float4 v1 = {r[4], r[5], r[6], r[7]};
  float* op = out + (size_t)t * HDIM + c;
  *(float4*)op = v0;
  *(float4*)(op + 4) = v1;
}

// --- expert GEMMs: r13 loop + r16 epilogue (frozen). FUSET: WprojT in tail ---
// 128x256 tile, BK=32, 3-slot ring (72KB), 8 waves (2M x 4N), wave tile 64x64,
// acc[4][4]. Per K-tile: vmcnt(3) -> s_barrier -> 8 ds_read(slot t) -> stage
// t+2 (3 gload16 -> slot t-1) -> setprio(1) 16 MFMA. Last tile vmcnt(0) (r3/r4);
// vmcnt BEFORE barrier (r7); WAR: slot t-1's reads preceded bar(t). Swizzle
// (r2/r9 pair, 0 conflicts). nt-fastest XCD work order. Epilogue: LDS bounce
// (pitch 260) -> coalesced ushort4 stores. GEMM2 writes UNWEIGHTED split-K=2
// partials to y; combine applies weights (no atomics).
// FUSET tail blocks: TWO side-by-side v2 tile_256 transposes per 512-thr block
// (r20: tile_512's ushort4 writes were an 8-way bank conflict, +1.3M cycles;
// v2's scalar-store pattern is the measured-0-conflict one).
template <int KD, int KSPL, int NTP, bool GATHER, bool SQRELU, bool FUSET>
__global__ __launch_bounds__(512, 4) void moe_gemm_kernel(
    const unsigned short* __restrict__ A0, const unsigned short* __restrict__ B0,
    const int* __restrict__ counts, const int* __restrict__ pair_token,
    unsigned short* __restrict__ Cout,
    const float* __restrict__ tin, unsigned short* __restrict__ tout) {
  constexpr int ND = SQRELU ? FFDIM : HDIM;
  constexpr int KLEN = KD / KSPL;
  constexpr int NTILES = KLEN / 32;
  constexpr int NBG = NTP * KSPL * MAXMT;

  __shared__ char lds[73728];          // 3 slots x (A 8KB + B 16KB); 2x33792B for transpose

  if (FUSET && blockIdx.x >= (unsigned)NBG) {
    // Wproj: [4096][1024] per expert -> 16 my x 16 nx = 256 tiles; 2 tiles/block
    int half = threadIdx.x >> 8;                   // 0 or 1
    int tau = (blockIdx.x - NBG) * 2 + half;
    int e = tau >> 8, r = tau & 255;
    unsigned short* tb = (unsigned short*)lds + half * (64 * 264);
    transpose_tile_256(tin + (size_t)e * FFDIM * HDIM, tout + (size_t)e * FFDIM * HDIM,
                       FFDIM, HDIM, r >> 4, r & 15, tb, threadIdx.x & 255);
    return;
  }

  // XCD-chunked bijective swizzle over the GEMM sub-domain (NBG % 8 == 0); nt fastest
  int d = blockIdx.x;
  int w = (d & 7) * (NBG >> 3) + (d >> 3);
  int nt = w % NTP;
  int rest = w / NTP;
  int ks = rest % KSPL;
  int mt = rest / KSPL;

  // ---- expert-tile search (wave-uniform) ----
  int eSel = -1, tloc = 0, segstart = 0, segcnt = 0;
  {
    int cumt = 0, acc = 0;
#pragma unroll
    for (int ee = 0; ee < NEXP; ee++) {
      int c = counts[ee];
      int ntl = (c + 127) >> 7;
      if (eSel < 0 && mt < cumt + ntl) { eSel = ee; tloc = mt - cumt; segstart = acc; segcnt = c; }
      cumt += ntl; acc += c;
    }
  }
  if (eSel < 0) return;

  if (!SQRELU) Cout += (size_t)ks * NPAIR * HDIM;   // split-K partial buffer

  const unsigned short* B = B0 + (size_t)eSel * ND * KD + (size_t)ks * KLEN;
  const unsigned short* Abase = A0 + (size_t)ks * KLEN;

  int tid = threadIdx.x;
  int lane = tid & 63;
  int wv = tid >> 6;       // 0..7
  int wr = wv >> 2;        // 0..1  (M)
  int wc = wv & 3;         // 0..3  (N)
  int g  = lane >> 4;      // 0..3
  int lr = lane & 15;

  int srow = tid >> 2;                       // 0..127
  int schunk = (tid & 3) ^ ((tid >> 3) & 3); // pre-swizzled source chunk
  const unsigned short* aP;
  const unsigned short* bP[2];
  {
    int idx = tloc * 128 + srow;
    if (idx >= segcnt) idx = segcnt - 1;     // clamp pad rows
    int p = segstart + idx;
    size_t rowoff;
    if (GATHER) rowoff = (size_t)pair_token[p] * KD;
    else        rowoff = (size_t)p * KD;
    aP = Abase + rowoff + schunk * 8;
#pragma unroll
    for (int r = 0; r < 2; r++)
      bP[r] = B + (size_t)(nt * 256 + r * 128 + srow) * KD + schunk * 8;
  }

  const char* ldsc = lds;
  int ldsW = wv * 1024;                // wave-uniform (lane*16 added by HW)

  f32x4 acc[4][4];
#pragma unroll
  for (int i = 0; i < 4; i++)
#pragma unroll
    for (int j = 0; j < 4; j++) acc[i][j] = (f32x4){0.f, 0.f, 0.f, 0.f};

  int swz = (g ^ ((lr >> 1) & 3)) * 16;
  int abase0 = (wr * 64 + lr) * 64 + swz;            // + mi*1024
  int bbase0 = 8192 + (wc * 64 + lr) * 64 + swz;     // + nj*1024

  // prologue: stage tiles 0 and 1 into slots 0,1
#pragma unroll
  for (int t = 0; t < 2; t++) {
    int so = t * 24576;
    gload16(aP, ldsc + so + ldsW);
    gload16(bP[0], ldsc + so + 8192 + ldsW);
    gload16(bP[1], ldsc + so + 16384 + ldsW);
    aP += 32; bP[0] += 32; bP[1] += 32;
  }

  int rsOff = 0, rs2Off = 49152;
  for (int t = 0; t < NTILES; ++t) {
    if (t < NTILES - 1) {
      asm volatile("s_waitcnt vmcnt(3)" ::: "memory");
    } else {
      asm volatile("s_waitcnt vmcnt(0)" ::: "memory");
    }
    __builtin_amdgcn_s_barrier();
    __builtin_amdgcn_sched_barrier(0);

    short8 af[4], bf[4];
#pragma unroll
    for (int mi = 0; mi < 4; mi++)
      af[mi] = *(const short8*)(ldsc + rsOff + abase0 + mi * 1024);
#pragma unroll
    for (int nj = 0; nj < 4; nj++)
      bf[nj] = *(const short8*)(ldsc + rsOff + bbase0 + nj * 1024);

    if (t + 2 < NTILES) {              // stage tile t+2 into slot of tile t-1
      gload16(aP, ldsc + rs2Off + ldsW);
      gload16(bP[0], ldsc + rs2Off + 8192 + ldsW);
      gload16(bP[1], ldsc + rs2Off + 16384 + ldsW);
      aP += 32; bP[0] += 32; bP[1] += 32;
    }

    __builtin_amdgcn_s_setprio(1);
#pragma unroll
    for (int mi = 0; mi < 4; mi++)
#pragma unroll
      for (int nj = 0; nj < 4; nj++)
        acc[mi][nj] = __builtin_amdgcn_mfma_f32_16x16x32_bf16(af[mi], bf[nj], acc[mi][nj], 0, 0, 0);
    __builtin_amdgcn_s_setprio(0);

    rsOff  = (rsOff  == 49152) ? 0 : rsOff  + 24576;
    rs2Off = (rs2Off == 49152) ? 0 : rs2Off + 24576;
  }

  // ---- epilogue: LDS bounce -> coalesced ushort4 stores ----
  __syncthreads();                     // all waves done reading ring slots
  unsigned short* t2 = (unsigned short*)lds;   // [128][260]
#pragma unroll
  for (int mi = 0; mi < 4; mi++) {
#pragma unroll
    for (int q = 0; q < 4; q++) {
      int row = wr * 64 + mi * 16 + g * 4 + q;
#pragma unroll
      for (int nj = 0; nj < 4; nj++) {
        int col = wc * 64 + nj * 16 + lr;
        float v = acc[mi][nj][q];
        if (SQRELU) v = v > 0.f ? v * v : 0.f;
        t2[row * 260 + col] = f2bf(v);
      }
    }
  }
  __syncthreads();
  {
    int row = tid >> 2;                // 0..127
    int idx = tloc * 128 + row;
    if (idx < segcnt) {
      size_t base = (size_t)(segstart + idx) * ND + nt * 256;
      const unsigned short* src = t2 + row * 260;
#pragma unroll
      for (int i = 0; i < 16; i++) {
        int c = ((tid & 3) + i * 4) * 4;
        *(ushort4_t*)(Cout + base + c) = *(const ushort4_t*)(src + c);
      }
    }
  }
}

// ---------------- launch ----------------

extern "C" void kernel_launch(void* const* d_in, const int* in_sizes, int n_in,
                              void* d_out, int out_size, void* d_ws, size_t ws_size,
                              hipStream_t stream) {
  (void)in_sizes; (void)n_in; (void)out_size; (void)ws_size;
  const float* x     = (const float*)d_in[0];
  const float* Wg    = (const float*)d_in[1];
  const float* Wfc   = (const float*)d_in[2];
  const float* Wproj = (const float*)d_in[3];
  float* out = (float*)d_out;

  char* w = (char*)d_ws;
  size_t o = 0;
  auto take = [&](size_t n) { char* p = w + o; o += (n + 255) & ~(size_t)255; return p; };
  unsigned short* xb     = (unsigned short*)take((size_t)T_TOK * HDIM * 2);
  unsigned short* WfcT   = (unsigned short*)take((size_t)NEXP * FFDIM * HDIM * 2);
  unsigned short* WprojT = (unsigned short*)take((size_t)NEXP * HDIM * FFDIM * 2);
  unsigned short* h1     = (unsigned short*)take((size_t)NPAIR * FFDIM * 2);
  unsigned short* y      = (unsigned short*)take((size_t)2 * NPAIR * HDIM * 2);
  int*   sel_e      = (int*)take(T_TOK * 2 * 4);
  float* sel_w      = (float*)take(T_TOK * 2 * 4);
  int*   pair_token = (int*)take(NPAIR * 4);
  int*   pair_pos   = (int*)take(NPAIR * 4);
  int*   counts     = (int*)take(8 * 4);

  // A: router (1024 blocks, atomic-free) + Wfc transpose (2048 blocks), overlapped
  routerA_kernel<<<3072, 256, 0, stream>>>(x, Wg, xb, sel_e, sel_w, Wfc, WfcT);
  // B: single-block count + scatter via LDS cursors (no global atomics)
  count_scatter_kernel<<<1, 1024, 0, stream>>>(sel_e, counts, pair_token, pair_pos);

  // GEMM1 (1152 blocks) + Wproj transpose (1024 blocks, 2x tile_256 each) fused
  moe_gemm_kernel<HDIM, 1, FFDIM / 256, true, true, true>
      <<<(FFDIM / 256) * MAXMT + 1024, 512, 0, stream>>>(
          xb, WfcT, counts, pair_token, h1, Wproj, WprojT);
  // GEMM2: split-K=2 partials y (no atomics)
  moe_gemm_kernel<FFDIM, 2, HDIM / 256, false, false, false>
      <<<(HDIM / 256) * 2 * MAXMT, 512, 0, stream>>>(
          h1, WprojT, counts, pair_token, y, nullptr, nullptr);
  // combine: out[t] = w0*(y0[pos0]+y1[pos0]) + w1*(y0[pos1]+y1[pos1])
  combine_kernel<<<T_TOK * (HDIM / 8) / 256, 256, 0, stream>>>(y, pair_pos, sel_w, out);
}